// Round 5
// baseline (4363.357 us; speedup 1.0000x reference)
//
#include <hip/hip_runtime.h>

// ---------------------------------------------------------------------------
// MultiHeadedAttention w/ n-gram RNN heads + rel-pos embeddings.
// B=8 S=512 D=1024 H=8 DPH=128, MAX_REL=32, NG heads 4..7.
// ROUND 5: scalar pipeline with FP32 inputs/outputs (dtype bisection).
//   Theory: all float tensors are fp32 arrays (values bf16-quantized by the
//   harness); prior rounds read them as bf16 -> garbage incl. NaN.
// Internals: convert to bf16 once (lossless if values are bf16-quantized),
// fp32 accumulation, fp32 stores to d_out. Mask read as int32.
//
// ws (33,702,144 B): qb 8.39M | kb 8.39M | vb 8.39M | abuf(f32) 8.52M | relb 16.6K
//   ctx (bf16) aliases qb (qb dead after scores).
// d_out (fp32): out [0, 4.19M floats) | attn [4.19M, 20.97M floats).
//   rnnout (bf16 scratch) lives at start of attn region; fully overwritten
//   by scores' fp32 attn writes before av reads attn.
// ---------------------------------------------------------------------------

__device__ __forceinline__ float bf2f(unsigned short u) {
  return __uint_as_float(((unsigned)u) << 16);
}
__device__ __forceinline__ float lo16(unsigned u) {
  return __uint_as_float(u << 16);
}
__device__ __forceinline__ float hi16(unsigned u) {
  return __uint_as_float(u & 0xFFFF0000u);
}
__device__ __forceinline__ unsigned short f2bf(float f) {
  unsigned u = __float_as_uint(f);
  u += 0x7FFFu + ((u >> 16) & 1u);
  return (unsigned short)(u >> 16);
}

// ---------------------------------------------------------------------------
// K1: QKV projection, scalar fp32. Block = 16 m-rows x 256 n-cols, one tensor.
// grid (256, 12): y>>2 = tensor, y&3 = n-quarter. Outputs bf16 (B,H,S,128).
// ---------------------------------------------------------------------------
__global__ __launch_bounds__(256) void qkv_scalar(
    const float* __restrict__ x,
    const float* __restrict__ Wq, const float* __restrict__ bq,
    const float* __restrict__ Wk, const float* __restrict__ bk,
    const float* __restrict__ Wv, const float* __restrict__ bv,
    const int* __restrict__ mask,
    unsigned short* __restrict__ qb, unsigned short* __restrict__ kb,
    unsigned short* __restrict__ vb) {
  __shared__ float Xs[16 * 1024];   // k-major: Xs[k*16+i], 64 KB
  const int tid = threadIdx.x;
  const int m0 = blockIdx.x * 16;
  const int t = blockIdx.y >> 2;
  const int n = (blockIdx.y & 3) * 256 + tid;
  const float* W = (t == 0) ? Wq : (t == 1) ? Wk : Wv;
  const float* bias = (t == 0) ? bq : (t == 1) ? bk : bv;
  unsigned short* dst = (t == 0) ? qb : (t == 1) ? kb : vb;

  for (int c = tid; c < 16384; c += 256) {
    int i = c >> 10, k = c & 1023;
    Xs[k * 16 + i] = x[(size_t)(m0 + i) * 1024 + k];
  }
  __syncthreads();

  float acc[16];
#pragma unroll
  for (int i = 0; i < 16; ++i) acc[i] = 0.f;
  for (int k = 0; k < 1024; ++k) {
    float wv = W[(size_t)n * 1024 + k];
#pragma unroll
    for (int i = 0; i < 16; ++i) acc[i] += wv * Xs[k * 16 + i];
  }
  float bvv = bias[n];
  int hh = n >> 7, dc = n & 127;
#pragma unroll
  for (int i = 0; i < 16; ++i) {
    int m = m0 + i, b = m >> 9, s = m & 511;
    float val = acc[i] + bvv;
    if (mask[b * 512 + s]) val = 0.f;
    dst[((size_t)(b * 8 + hh) * 512 + s) * 128 + dc] = f2bf(val);
  }
}

// ---------------------------------------------------------------------------
// K2: rel_emb fp32 -> bf16 (65 x 128).
// ---------------------------------------------------------------------------
__global__ __launch_bounds__(256) void rel_to_bf16(
    const float* __restrict__ rel, unsigned short* __restrict__ relb) {
  int i = blockIdx.x * 256 + threadIdx.x;
  if (i < 65 * 128) relb[i] = f2bf(rel[i]);
}

// ---------------------------------------------------------------------------
// K3: bidirectional 2-step RNN, scalar. Block = (g, 8 s-rows), 128 threads.
// grid 6144 = 96 groups x 64 tiles. Weights fp32.
// ---------------------------------------------------------------------------
__global__ __launch_bounds__(128) void rnn_scalar(
    const unsigned short* __restrict__ qb, const unsigned short* __restrict__ kb,
    const unsigned short* __restrict__ vb,
    const float* __restrict__ Wihf, const float* __restrict__ Whhf,
    const float* __restrict__ bihf, const float* __restrict__ bhhf,
    const float* __restrict__ Wihb, const float* __restrict__ Whhb,
    const float* __restrict__ bihb, const float* __restrict__ bhhb,
    unsigned short* __restrict__ rnnout) {
  __shared__ float Xs[9 * 128];   // rows s0-1 .. s0+7
  __shared__ float H1[8 * 128];
  const int g = blockIdx.x >> 6;
  const int s0 = (blockIdx.x & 63) * 8;
  const int t = g >> 5, rem = g & 31, b = rem >> 2, h = (rem & 3) + 4;
  const unsigned short* src = (t == 0) ? qb : (t == 1) ? kb : vb;
  const size_t base = (size_t)(b * 8 + h) * 512;
  const int col = threadIdx.x;

  for (int r = 0; r < 9; ++r) {
    int s = s0 - 1 + r;
    Xs[r * 128 + col] = (s < 0) ? 0.f : bf2f(src[(base + s) * 128 + col]);
  }
  __syncthreads();
  const float cbF = bihf[col] + bhhf[col];
  const float cbB = bihb[col] + bhhb[col];

  float acc[8];
  // pass 1: h1f[j] = tanh(Wihf . x_{s-1} + cbF)
#pragma unroll
  for (int j = 0; j < 8; ++j) acc[j] = 0.f;
  for (int d = 0; d < 128; ++d) {
    float wv = Wihf[col * 128 + d];
#pragma unroll
    for (int j = 0; j < 8; ++j) acc[j] += wv * Xs[j * 128 + d];
  }
#pragma unroll
  for (int j = 0; j < 8; ++j) H1[j * 128 + col] = tanhf(acc[j] + cbF);
  __syncthreads();
  // pass 2: of[j] = tanh(Wihf . x_s + Whhf . h1f + cbF)
#pragma unroll
  for (int j = 0; j < 8; ++j) acc[j] = 0.f;
  for (int d = 0; d < 128; ++d) {
    float wv = Wihf[col * 128 + d];
#pragma unroll
    for (int j = 0; j < 8; ++j) acc[j] += wv * Xs[(j + 1) * 128 + d];
  }
  for (int d = 0; d < 128; ++d) {
    float wv = Whhf[col * 128 + d];
#pragma unroll
    for (int j = 0; j < 8; ++j) acc[j] += wv * H1[j * 128 + d];
  }
  float of[8];
#pragma unroll
  for (int j = 0; j < 8; ++j) of[j] = tanhf(acc[j] + cbF);
  __syncthreads();
  // pass 3: h1b[j] = tanh(Wihb . x_s + cbB)
#pragma unroll
  for (int j = 0; j < 8; ++j) acc[j] = 0.f;
  for (int d = 0; d < 128; ++d) {
    float wv = Wihb[col * 128 + d];
#pragma unroll
    for (int j = 0; j < 8; ++j) acc[j] += wv * Xs[(j + 1) * 128 + d];
  }
#pragma unroll
  for (int j = 0; j < 8; ++j) H1[j * 128 + col] = tanhf(acc[j] + cbB);
  __syncthreads();
  // pass 4: ob[j] = tanh(Wihb . x_{s-1} + Whhb . h1b + cbB); store of+ob
#pragma unroll
  for (int j = 0; j < 8; ++j) acc[j] = 0.f;
  for (int d = 0; d < 128; ++d) {
    float wv = Wihb[col * 128 + d];
#pragma unroll
    for (int j = 0; j < 8; ++j) acc[j] += wv * Xs[j * 128 + d];
  }
  for (int d = 0; d < 128; ++d) {
    float wv = Whhb[col * 128 + d];
#pragma unroll
    for (int j = 0; j < 8; ++j) acc[j] += wv * H1[j * 128 + d];
  }
#pragma unroll
  for (int j = 0; j < 8; ++j) {
    float val = of[j] + tanhf(acc[j] + cbB);
    rnnout[((size_t)g * 512 + s0 + j) * 128 + col] = f2bf(val);
  }
}

// ---------------------------------------------------------------------------
// K4: copy RNN results back into qb/kb/vb.
// ---------------------------------------------------------------------------
__global__ __launch_bounds__(256) void rnn_copyback(
    const unsigned short* __restrict__ rnnout,
    unsigned short* __restrict__ qb, unsigned short* __restrict__ kb,
    unsigned short* __restrict__ vb) {
  int idx = blockIdx.x * 256 + threadIdx.x;   // 6,291,456 total
  int g = idx >> 16;
  int r2 = idx & 65535;
  int s = r2 >> 7, col = r2 & 127;
  int t = g >> 5, rem = g & 31, b = rem >> 2, h = (rem & 3) + 4;
  unsigned short val = rnnout[idx];
  size_t off = ((size_t)(b * 8 + h) * 512 + s) * 128 + col;
  if (t == 0) qb[off] = val;
  else if (t == 1) kb[off] = val;
  else vb[off] = val;
}

// ---------------------------------------------------------------------------
// K5: scores + softmax + bucket sums. Block = (bh, 8 q-rows), 256 threads.
// grid 4096 = 64 bh x 64 q-tiles. attn written fp32; abuf fp32 (stride 65).
// ---------------------------------------------------------------------------
__global__ __launch_bounds__(256) void scores_scalar(
    const unsigned short* __restrict__ qb, const unsigned short* __restrict__ kb,
    const unsigned short* __restrict__ relb, const int* __restrict__ mask,
    float* __restrict__ attn, float* __restrict__ abuf) {
  __shared__ __align__(16) unsigned KsU[256 * 65];  // 256 rows x 65 uints (pad)
  __shared__ float sc[8 * 512];
  __shared__ unsigned qvU[8 * 64];
  __shared__ float Ps[8 * 65];
  __shared__ float rsrow[8];
  const int tid = threadIdx.x;
  const int bh = blockIdx.x >> 6;
  const int q0 = (blockIdx.x & 63) * 8;
  const int b = bh >> 3;
  const size_t qrow0 = (size_t)bh * 512 + q0;
  const unsigned* qbU = (const unsigned*)qb;
  const unsigned* kbU = (const unsigned*)kb;
  const unsigned* relU = (const unsigned*)relb;

  for (int c = tid; c < 512; c += 256) {
    int r = c >> 6, dp = c & 63;
    qvU[c] = qbU[(qrow0 + r) * 64 + dp];
  }

  for (int chunk = 0; chunk < 2; ++chunk) {
    __syncthreads();
    for (int c = tid; c < 256 * 64; c += 256) {
      int r = c >> 6, dp = c & 63;
      KsU[r * 65 + dp] = kbU[((size_t)bh * 512 + chunk * 256 + r) * 64 + dp];
    }
    __syncthreads();
    float acc[8];
#pragma unroll
    for (int r = 0; r < 8; ++r) acc[r] = 0.f;
    for (int dp = 0; dp < 64; ++dp) {
      unsigned ku = KsU[tid * 65 + dp];
      float k0 = lo16(ku), k1 = hi16(ku);
#pragma unroll
      for (int r = 0; r < 8; ++r) {
        unsigned qu = qvU[r * 64 + dp];
        acc[r] += k0 * lo16(qu) + k1 * hi16(qu);
      }
    }
    int k = chunk * 256 + tid;
#pragma unroll
    for (int r = 0; r < 8; ++r) sc[r * 512 + k] = acc[r];
  }
  __syncthreads();
  // rel rows (bf16 pairs) into KsU, then Ps[q][rr] = q . rel[rr]
  for (int c = tid; c < 65 * 64; c += 256) {
    int r = c >> 6, dp = c & 63;
    KsU[r * 65 + dp] = relU[r * 64 + dp];
  }
  __syncthreads();
  for (int c = tid; c < 520; c += 256) {
    int q = c / 65, rr = c % 65;
    float a = 0.f;
    for (int dp = 0; dp < 64; ++dp) {
      unsigned ru = KsU[rr * 65 + dp], qu = qvU[q * 64 + dp];
      a += lo16(ru) * lo16(qu) + hi16(ru) * hi16(qu);
    }
    Ps[c] = a;
  }
  __syncthreads();
  const float rscale = 0.08838834764831845f;  // 1/sqrt(128)
#pragma unroll
  for (int kk = 0; kk < 2; ++kk) {
    int k = kk * 256 + tid;
    float cm = mask[b * 512 + k] ? -1e9f : 0.f;
#pragma unroll
    for (int r = 0; r < 8; ++r) {
      int qg = q0 + r;
      int d = k - qg;
      int rr = min(max(d, -32), 32) + 32;
      sc[r * 512 + k] = (sc[r * 512 + k] + Ps[r * 65 + rr]) * rscale + cm;
    }
  }
  __syncthreads();
  if (tid < 8) {
    int r = tid;
    float mx = -1e30f;
    for (int k = 0; k < 512; ++k) mx = fmaxf(mx, sc[r * 512 + k]);
    float sum = 0.f;
    for (int k = 0; k < 512; ++k) {
      float e = __expf(sc[r * 512 + k] - mx);
      sc[r * 512 + k] = e;
      sum += e;
    }
    rsrow[r] = 1.f / sum;
  }
  __syncthreads();
#pragma unroll
  for (int kk = 0; kk < 2; ++kk) {
    int k = kk * 256 + tid;
#pragma unroll
    for (int r = 0; r < 8; ++r) {
      float at = sc[r * 512 + k] * rsrow[r];
      sc[r * 512 + k] = at;
      attn[(qrow0 + r) * 512 + k] = at;
    }
  }
  __syncthreads();
  if (tid < 65) {
    for (int r = 0; r < 8; ++r) {
      int qg = q0 + r;
      float val = 0.f;
      if (tid == 0) {
        for (int k = 0; k <= qg - 32 && k < 512; ++k) val += sc[r * 512 + k];
      } else if (tid == 64) {
        for (int k = qg + 32; k < 512; ++k) {
          if (k >= 0) val += sc[r * 512 + k];
        }
      } else {
        int k = qg + (tid - 32);
        if (k >= 0 && k < 512) val = sc[r * 512 + k];
      }
      abuf[(qrow0 + r) * 65 + tid] = val;
    }
  }
}

// ---------------------------------------------------------------------------
// K6: ctx = attn @ v + a @ rel. Block = (bh, 8 q-rows), 128 threads (d).
// ---------------------------------------------------------------------------
__global__ __launch_bounds__(128) void av_scalar(
    const float* __restrict__ attn, const float* __restrict__ abuf,
    const unsigned short* __restrict__ vb, const unsigned short* __restrict__ relb,
    unsigned short* __restrict__ ctx) {
  __shared__ float at[8 * 512];
  __shared__ float ar[8 * 65];
  const int tid = threadIdx.x;
  const int bh = blockIdx.x >> 6;
  const int q0 = (blockIdx.x & 63) * 8;
  const size_t qrow0 = (size_t)bh * 512 + q0;

  for (int c = tid; c < 4096; c += 128) {
    int r = c >> 9, k = c & 511;
    at[c] = attn[(qrow0 + r) * 512 + k];
  }
  for (int c = tid; c < 520; c += 128) {
    int r = c / 65, rr = c % 65;
    ar[c] = abuf[(qrow0 + r) * 65 + rr];
  }
  __syncthreads();

  float acc[8];
#pragma unroll
  for (int r = 0; r < 8; ++r) acc[r] = 0.f;
  const int d = tid;
  for (int k = 0; k < 512; ++k) {
    float vv = bf2f(vb[((size_t)bh * 512 + k) * 128 + d]);
#pragma unroll
    for (int r = 0; r < 8; ++r) acc[r] += at[r * 512 + k] * vv;
  }
  for (int rr = 0; rr < 65; ++rr) {
    float rv = bf2f(relb[rr * 128 + d]);
#pragma unroll
    for (int r = 0; r < 8; ++r) acc[r] += ar[r * 65 + rr] * rv;
  }
  const int b = bh >> 3, h = bh & 7;
#pragma unroll
  for (int r = 0; r < 8; ++r)
    ctx[((size_t)(b * 512 + q0 + r)) * 1024 + h * 128 + d] = f2bf(acc[r]);
}

// ---------------------------------------------------------------------------
// K7: out = ctx @ Wo^T + bo; ctx bf16, Wo/bo/out fp32. grid (256, 4).
// ---------------------------------------------------------------------------
__global__ __launch_bounds__(256) void out_scalar(
    const unsigned short* __restrict__ ctx, const float* __restrict__ Wo,
    const float* __restrict__ bo, float* __restrict__ outp) {
  __shared__ __align__(16) unsigned short Xs[16 * 1024];
  const int tid = threadIdx.x;
  const int m0 = blockIdx.x * 16;
  const int n = blockIdx.y * 256 + tid;

  for (int c = tid; c < 16384; c += 256) {
    int i = c >> 10, k = c & 1023;
    Xs[k * 16 + i] = ctx[(size_t)(m0 + i) * 1024 + k];
  }
  __syncthreads();

  float acc[16];
#pragma unroll
  for (int i = 0; i < 16; ++i) acc[i] = 0.f;
  const uint4* XsU4 = (const uint4*)Xs;
  for (int k = 0; k < 1024; ++k) {
    float wv = Wo[(size_t)n * 1024 + k];
    uint4 ua = XsU4[k * 2], ub = XsU4[k * 2 + 1];
    acc[0]  += wv * lo16(ua.x); acc[1]  += wv * hi16(ua.x);
    acc[2]  += wv * lo16(ua.y); acc[3]  += wv * hi16(ua.y);
    acc[4]  += wv * lo16(ua.z); acc[5]  += wv * hi16(ua.z);
    acc[6]  += wv * lo16(ua.w); acc[7]  += wv * hi16(ua.w);
    acc[8]  += wv * lo16(ub.x); acc[9]  += wv * hi16(ub.x);
    acc[10] += wv * lo16(ub.y); acc[11] += wv * hi16(ub.y);
    acc[12] += wv * lo16(ub.z); acc[13] += wv * hi16(ub.z);
    acc[14] += wv * lo16(ub.w); acc[15] += wv * hi16(ub.w);
  }
  float bvv = bo[n];
#pragma unroll
  for (int i = 0; i < 16; ++i)
    outp[(size_t)(m0 + i) * 1024 + n] = acc[i] + bvv;
}

// ---------------------------------------------------------------------------
extern "C" void kernel_launch(void* const* d_in, const int* in_sizes, int n_in,
                              void* d_out, int out_size, void* d_ws, size_t ws_size,
                              hipStream_t stream) {
  const float* x    = (const float*)d_in[0];
  const int*   mask = (const int*)d_in[1];
  const float* Wq   = (const float*)d_in[2];
  const float* bq   = (const float*)d_in[3];
  const float* Wk   = (const float*)d_in[4];
  const float* bk   = (const float*)d_in[5];
  const float* Wv   = (const float*)d_in[6];
  const float* bv   = (const float*)d_in[7];
  const float* Wo   = (const float*)d_in[8];
  const float* bo   = (const float*)d_in[9];
  const float* rel  = (const float*)d_in[10];
  const float* Wihf = (const float*)d_in[11];
  const float* Whhf = (const float*)d_in[12];
  const float* bihf = (const float*)d_in[13];
  const float* bhhf = (const float*)d_in[14];
  const float* Wihb = (const float*)d_in[15];
  const float* Whhb = (const float*)d_in[16];
  const float* bihb = (const float*)d_in[17];
  const float* bhhb = (const float*)d_in[18];

  // ws: 33,702,144 bytes
  char* ws = (char*)d_ws;
  unsigned short* qb   = (unsigned short*)(ws + 0);          // 8,388,608 B
  unsigned short* kb   = (unsigned short*)(ws + 8388608);    // 8,388,608 B
  unsigned short* vb   = (unsigned short*)(ws + 16777216);   // 8,388,608 B
  float*          abuf = (float*)(ws + 25165824);            // 8,519,680 B
  unsigned short* relb = (unsigned short*)(ws + 33685504);   //    16,640 B
  unsigned short* ctx  = qb;   // qb dead after scores_scalar

  float* outp  = (float*)d_out;
  float* attnF = outp + 4194304;                 // (B,H,S,S) fp32
  unsigned short* rnnout = (unsigned short*)attnF;  // 12.6 MB bf16 scratch;
  // fully overwritten by scores_scalar's 67 MB fp32 attn writes before read.

  qkv_scalar<<<dim3(256, 12), dim3(256), 0, stream>>>(
      x, Wq, bq, Wk, bk, Wv, bv, mask, qb, kb, vb);
  rel_to_bf16<<<dim3(33), dim3(256), 0, stream>>>(rel, relb);
  rnn_scalar<<<dim3(6144), dim3(128), 0, stream>>>(
      qb, kb, vb, Wihf, Whhf, bihf, bhhf, Wihb, Whhb, bihb, bhhb, rnnout);
  rnn_copyback<<<dim3(24576), dim3(256), 0, stream>>>(rnnout, qb, kb, vb);
  scores_scalar<<<dim3(4096), dim3(256), 0, stream>>>(qb, kb, relb, mask, attnF, abuf);
  av_scalar<<<dim3(4096), dim3(128), 0, stream>>>(attnF, abuf, vb, relb, ctx);
  out_scalar<<<dim3(256, 4), dim3(256), 0, stream>>>(ctx, Wo, bo, outp);
}

// Round 6
// 439.079 us; speedup vs baseline: 9.9375x; 9.9375x over previous
//
#include <hip/hip_runtime.h>

// ---------------------------------------------------------------------------
// MultiHeadedAttention w/ n-gram RNN heads + rel-pos embeddings. MFMA version.
// B=8 S=512 D=1024 H=8 DPH=128, MAX_REL=32, NG heads 4..7.
// I/O: float tensors are FP32 (verified R5); mask int32. Internals bf16+MFMA.
//
// ws (31,498,752 B): qb | kb | vT | abuf | relb | relT; ctx aliases qb.
// d_out scratch: vb, rnnout live in the attn region (fp32 attn fully
// overwrites them in scores before av_ctx reads attn).
// ---------------------------------------------------------------------------

typedef __bf16 bf16x8 __attribute__((ext_vector_type(8)));
typedef float f32x4 __attribute__((ext_vector_type(4)));

#define MFMA16(a, b, c) __builtin_amdgcn_mfma_f32_16x16x32_bf16(a, b, c, 0, 0, 0)

__device__ __forceinline__ unsigned short f2bf(float f) {
  unsigned u = __float_as_uint(f);
  u += 0x7FFFu + ((u >> 16) & 1u);
  return (unsigned short)(u >> 16);
}
__device__ __forceinline__ uint2 pack4(float4 f) {
  uint2 r;
  r.x = (unsigned)f2bf(f.x) | ((unsigned)f2bf(f.y) << 16);
  r.y = (unsigned)f2bf(f.z) | ((unsigned)f2bf(f.w) << 16);
  return r;
}

// ---------------------------------------------------------------------------
// K1: QKV projection. GEMM (4096 x 3072virt x 1024), 128x128 tiles, MFMA.
// fp32 inputs converted to bf16 during LDS staging. Epilogue: +bias, mask->0,
// scatter bf16 to (B,H,S,128); v also transposed into vT.
// ---------------------------------------------------------------------------
__global__ __launch_bounds__(256) void qkv_proj(
    const float* __restrict__ x,
    const float* __restrict__ Wq, const float* __restrict__ bq,
    const float* __restrict__ Wk, const float* __restrict__ bk,
    const float* __restrict__ Wv, const float* __restrict__ bv,
    const int* __restrict__ mask,
    unsigned short* __restrict__ qb, unsigned short* __restrict__ kb,
    unsigned short* __restrict__ vb, unsigned short* __restrict__ vT) {
  __shared__ __align__(16) unsigned short As[128 * 64];
  __shared__ __align__(16) unsigned short Bs[128 * 64];
  const int bm = blockIdx.x & 31;
  const int bn = blockIdx.x >> 5;           // 0..23
  const int t = bn >> 3;                    // 0:q 1:k 2:v
  const int nloc0 = (bn & 7) * 128;
  const float* W = (t == 0) ? Wq : (t == 1) ? Wk : Wv;
  const float* bias = (t == 0) ? bq : (t == 1) ? bk : bv;
  const int tid = threadIdx.x;
  const int lane = tid & 63, w = tid >> 6;
  const int wm = (w >> 1) * 64, wn = (w & 1) * 64;
  const int lanelo = lane & 15, quad = lane >> 4;
  const int row0 = bm * 128;

  f32x4 acc[4][4];
  const f32x4 zf = {0.f, 0.f, 0.f, 0.f};
#pragma unroll
  for (int i = 0; i < 4; ++i)
#pragma unroll
    for (int j = 0; j < 4; ++j) acc[i][j] = zf;

  for (int kt = 0; kt < 16; ++kt) {
#pragma unroll
    for (int p = 0; p < 8; ++p) {
      int c = p * 256 + tid;         // 2048 chunks of 4 floats per buffer
      int r = c >> 4, cc = c & 15;
      float4 fa = *(const float4*)(x + (size_t)(row0 + r) * 1024 + kt * 64 + cc * 4);
      float4 fb = *(const float4*)(W + (size_t)(nloc0 + r) * 1024 + kt * 64 + cc * 4);
      *(uint2*)(&As[c * 4]) = pack4(fa);
      *(uint2*)(&Bs[c * 4]) = pack4(fb);
    }
    __syncthreads();
#pragma unroll
    for (int ks = 0; ks < 2; ++ks) {
      bf16x8 a[4], bb[4];
#pragma unroll
      for (int i = 0; i < 4; ++i)
        a[i] = *(const bf16x8*)(&As[(wm + i * 16 + lanelo) * 64 + ks * 32 + quad * 8]);
#pragma unroll
      for (int j = 0; j < 4; ++j)
        bb[j] = *(const bf16x8*)(&Bs[(wn + j * 16 + lanelo) * 64 + ks * 32 + quad * 8]);
#pragma unroll
      for (int i = 0; i < 4; ++i)
#pragma unroll
        for (int j = 0; j < 4; ++j) acc[i][j] = MFMA16(a[i], bb[j], acc[i][j]);
    }
    __syncthreads();
  }
#pragma unroll
  for (int i = 0; i < 4; ++i) {
#pragma unroll
    for (int j = 0; j < 4; ++j) {
      int jj = nloc0 + wn + j * 16 + lanelo;   // 0..1023 within tensor
      int hh = jj >> 7, dc = jj & 127;
      float bvv = bias[jj];
#pragma unroll
      for (int r = 0; r < 4; ++r) {
        int m = row0 + wm + i * 16 + quad * 4 + r;
        int b = m >> 9, s = m & 511;
        float val = acc[i][j][r] + bvv;
        if (mask[b * 512 + s]) val = 0.f;
        unsigned short o = f2bf(val);
        size_t off = ((size_t)(b * 8 + hh) * 512 + s) * 128 + dc;
        if (t == 0) qb[off] = o;
        else if (t == 1) kb[off] = o;
        else {
          vb[off] = o;
          vT[((size_t)(b * 8 + hh) * 128 + dc) * 512 + s] = o;
        }
      }
    }
  }
}

// ---------------------------------------------------------------------------
// K2: rel prep: relb (65x128 bf16 row-major), relT (128x96 bf16, zero-pad).
// ---------------------------------------------------------------------------
__global__ __launch_bounds__(256) void prep_rel(
    const float* __restrict__ rel, unsigned short* __restrict__ relb,
    unsigned short* __restrict__ relT) {
  int i = blockIdx.x * 256 + threadIdx.x;
  if (i < 65 * 128) relb[i] = f2bf(rel[i]);
  if (i < 128 * 96) {
    int d = i / 96, r = i - d * 96;
    relT[i] = (r < 65) ? f2bf(rel[r * 128 + d]) : (unsigned short)0;
  }
}

// ---------------------------------------------------------------------------
// K3: fused bidirectional 2-step RNN on heads 4..7 of q,k,v. MFMA.
// grid 768 = 96 groups x 8 tiles of 64 positions. fp32 weights -> bf16 LDS.
// ---------------------------------------------------------------------------
__global__ __launch_bounds__(256) void rnn_fused(
    const unsigned short* __restrict__ qb, const unsigned short* __restrict__ kb,
    const unsigned short* __restrict__ vb,
    const float* __restrict__ Wihf, const float* __restrict__ Whhf,
    const float* __restrict__ bihf, const float* __restrict__ bhhf,
    const float* __restrict__ Wihb, const float* __restrict__ Whhb,
    const float* __restrict__ bihb, const float* __restrict__ bhhb,
    unsigned short* __restrict__ rnn_out) {
  __shared__ __align__(16) unsigned short X[65 * 128];   // rows s0-1 .. s0+63
  __shared__ __align__(16) unsigned short Wi[128 * 128];
  __shared__ __align__(16) unsigned short Wh[128 * 128];
  __shared__ __align__(16) unsigned short H1[64 * 128];
  __shared__ float cbf[128], cbb[128];

  const int gid = blockIdx.x;
  const int tile = gid & 7;
  const int g = gid >> 3;              // 0..95
  const int t = g >> 5;
  const int rem = g & 31;
  const int b = rem >> 2, h = (rem & 3) + 4;
  const int s0 = tile * 64;
  const unsigned short* src = (t == 0) ? qb : (t == 1) ? kb : vb;
  const size_t rowbase = (size_t)(b * 8 + h) * 512;
  const int tid = threadIdx.x;

  for (int c = tid; c < 65 * 16; c += 256) {   // X: 65 rows x 16 uint4
    int r = c >> 4, cc = c & 15;
    uint4 v4;
    if (r == 0 && s0 == 0) v4 = make_uint4(0, 0, 0, 0);
    else v4 = *(const uint4*)(src + (rowbase + (s0 - 1 + r)) * 128 + cc * 8);
    *(uint4*)(&X[c * 8]) = v4;
  }
#pragma unroll
  for (int p = 0; p < 16; ++p) {       // weights: 4096 chunks of 4 floats each
    int c = p * 256 + tid;
    *(uint2*)(&Wi[c * 4]) = pack4(*(const float4*)(Wihf + c * 4));
    *(uint2*)(&Wh[c * 4]) = pack4(*(const float4*)(Whhf + c * 4));
  }
  if (tid < 128) {
    cbf[tid] = bihf[tid] + bhhf[tid];
    cbb[tid] = bihb[tid] + bhhb[tid];
  }
  __syncthreads();

  const int lane = tid & 63, w = tid >> 6;
  const int lanelo = lane & 15, quad = lane >> 4;
  const int marow = w * 16 + lanelo;
  const f32x4 zf = {0.f, 0.f, 0.f, 0.f};

  // ---- forward h1 = tanh(Wihf x_{s-1} + cbf) ----
  f32x4 g1[8];
#pragma unroll
  for (int j = 0; j < 8; ++j) g1[j] = zf;
#pragma unroll
  for (int ks = 0; ks < 4; ++ks) {
    bf16x8 a = *(const bf16x8*)(&X[marow * 128 + ks * 32 + quad * 8]);
#pragma unroll
    for (int j = 0; j < 8; ++j) {
      bf16x8 bb = *(const bf16x8*)(&Wi[(j * 16 + lanelo) * 128 + ks * 32 + quad * 8]);
      g1[j] = MFMA16(a, bb, g1[j]);
    }
  }
#pragma unroll
  for (int j = 0; j < 8; ++j) {
    int col = j * 16 + lanelo;
    float cb = cbf[col];
#pragma unroll
    for (int i = 0; i < 4; ++i) {
      int row = w * 16 + quad * 4 + i;
      H1[row * 128 + col] = f2bf(tanhf(g1[j][i] + cb));
    }
  }
  __syncthreads();
  // ---- forward out = tanh(Wihf x_s + Whhf h1 + cbf) ----
  f32x4 a2[8];
#pragma unroll
  for (int j = 0; j < 8; ++j) a2[j] = zf;
#pragma unroll
  for (int ks = 0; ks < 4; ++ks) {
    bf16x8 a = *(const bf16x8*)(&X[(marow + 1) * 128 + ks * 32 + quad * 8]);
#pragma unroll
    for (int j = 0; j < 8; ++j) {
      bf16x8 bb = *(const bf16x8*)(&Wi[(j * 16 + lanelo) * 128 + ks * 32 + quad * 8]);
      a2[j] = MFMA16(a, bb, a2[j]);
    }
  }
#pragma unroll
  for (int ks = 0; ks < 4; ++ks) {
    bf16x8 a = *(const bf16x8*)(&H1[marow * 128 + ks * 32 + quad * 8]);
#pragma unroll
    for (int j = 0; j < 8; ++j) {
      bf16x8 bb = *(const bf16x8*)(&Wh[(j * 16 + lanelo) * 128 + ks * 32 + quad * 8]);
      a2[j] = MFMA16(a, bb, a2[j]);
    }
  }
  float outF[8][4];
#pragma unroll
  for (int j = 0; j < 8; ++j) {
    int col = j * 16 + lanelo;
    float cb = cbf[col];
#pragma unroll
    for (int i = 0; i < 4; ++i) outF[j][i] = tanhf(a2[j][i] + cb);
  }
  __syncthreads();
#pragma unroll
  for (int p = 0; p < 16; ++p) {   // restage backward weights
    int c = p * 256 + tid;
    *(uint2*)(&Wi[c * 4]) = pack4(*(const float4*)(Wihb + c * 4));
    *(uint2*)(&Wh[c * 4]) = pack4(*(const float4*)(Whhb + c * 4));
  }
  __syncthreads();
  // ---- backward h1b = tanh(Wihb x_s + cbb) ----
#pragma unroll
  for (int j = 0; j < 8; ++j) g1[j] = zf;
#pragma unroll
  for (int ks = 0; ks < 4; ++ks) {
    bf16x8 a = *(const bf16x8*)(&X[(marow + 1) * 128 + ks * 32 + quad * 8]);
#pragma unroll
    for (int j = 0; j < 8; ++j) {
      bf16x8 bb = *(const bf16x8*)(&Wi[(j * 16 + lanelo) * 128 + ks * 32 + quad * 8]);
      g1[j] = MFMA16(a, bb, g1[j]);
    }
  }
#pragma unroll
  for (int j = 0; j < 8; ++j) {
    int col = j * 16 + lanelo;
    float cb = cbb[col];
#pragma unroll
    for (int i = 0; i < 4; ++i) {
      int row = w * 16 + quad * 4 + i;
      H1[row * 128 + col] = f2bf(tanhf(g1[j][i] + cb));
    }
  }
  __syncthreads();
  // ---- backward out + combine + store ----
#pragma unroll
  for (int j = 0; j < 8; ++j) a2[j] = zf;
#pragma unroll
  for (int ks = 0; ks < 4; ++ks) {
    bf16x8 a = *(const bf16x8*)(&X[marow * 128 + ks * 32 + quad * 8]);
#pragma unroll
    for (int j = 0; j < 8; ++j) {
      bf16x8 bb = *(const bf16x8*)(&Wi[(j * 16 + lanelo) * 128 + ks * 32 + quad * 8]);
      a2[j] = MFMA16(a, bb, a2[j]);
    }
  }
#pragma unroll
  for (int ks = 0; ks < 4; ++ks) {
    bf16x8 a = *(const bf16x8*)(&H1[marow * 128 + ks * 32 + quad * 8]);
#pragma unroll
    for (int j = 0; j < 8; ++j) {
      bf16x8 bb = *(const bf16x8*)(&Wh[(j * 16 + lanelo) * 128 + ks * 32 + quad * 8]);
      a2[j] = MFMA16(a, bb, a2[j]);
    }
  }
#pragma unroll
  for (int j = 0; j < 8; ++j) {
    int col = j * 16 + lanelo;
    float cb = cbb[col];
#pragma unroll
    for (int i = 0; i < 4; ++i) {
      int row = w * 16 + quad * 4 + i;
      float val = outF[j][i] + tanhf(a2[j][i] + cb);
      rnn_out[((size_t)g * 512 + s0 + row) * 128 + col] = f2bf(val);
    }
  }
}

// ---------------------------------------------------------------------------
// K4: copy rnn results back into qb/kb (+vT for v).
// ---------------------------------------------------------------------------
__global__ __launch_bounds__(256) void rnn_copyback(
    const unsigned short* __restrict__ rnn_out,
    unsigned short* __restrict__ qb, unsigned short* __restrict__ kb,
    unsigned short* __restrict__ vT) {
  int idx = blockIdx.x * 256 + threadIdx.x;   // 6,291,456
  int g = idx >> 16;
  int r2 = idx & 65535;
  int s = r2 >> 7, col = r2 & 127;
  int t = g >> 5, rem = g & 31, b = rem >> 2, h = (rem & 3) + 4;
  unsigned short val = rnn_out[idx];
  size_t off = ((size_t)(b * 8 + h) * 512 + s) * 128 + col;
  if (t == 0) qb[off] = val;
  else if (t == 1) kb[off] = val;
  else vT[((size_t)(b * 8 + h) * 128 + col) * 512 + s] = val;
}

// ---------------------------------------------------------------------------
// K5: scores + softmax + bucket sums. MFMA. One block per (b,h,64-q tile).
// attn written fp32 to d_out; buckets bf16 (stride 96, cols 65..95 zeroed).
// ---------------------------------------------------------------------------
__global__ __launch_bounds__(256) void scores_softmax(
    const unsigned short* __restrict__ qbuf, const unsigned short* __restrict__ kbuf,
    const unsigned short* __restrict__ relb, const int* __restrict__ mask,
    float* __restrict__ attn_out, unsigned short* __restrict__ abuf) {
  __shared__ __align__(16) unsigned short As[64 * 128];
  __shared__ __align__(16) unsigned short Bs[512 * 32];
  __shared__ float Ps[64 * 80];
  __shared__ float cmask[512];
  const int idx = blockIdx.x;
  const int qt = idx & 7, bh = idx >> 3, b = bh >> 3;
  const int q0 = qt * 64;
  const size_t qrow0 = (size_t)bh * 512 + q0;
  const int tid = threadIdx.x;

  for (int i = tid; i < 64 * 96; i += 256) abuf[qrow0 * 96 + i] = 0;
  for (int c = tid; c < 1024; c += 256) {
    int r = c >> 4, cc = c & 15;
    *(uint4*)(&As[c * 8]) = *(const uint4*)(qbuf + (qrow0 + r) * 128 + cc * 8);
  }
  for (int i = tid; i < 512; i += 256) cmask[i] = mask[b * 512 + i] ? -1e9f : 0.f;
  __syncthreads();

  const int lane = tid & 63, w = tid >> 6;
  const int lanelo = lane & 15, quad = lane >> 4;
  const f32x4 zf = {0.f, 0.f, 0.f, 0.f};

  // ---- P: p[q][r] = q . rel[r], r<65 (pad to 80) ----
  f32x4 pacc[5];
#pragma unroll
  for (int j = 0; j < 5; ++j) pacc[j] = zf;
  for (int ks = 0; ks < 4; ++ks) {
    for (int c = tid; c < 320; c += 256) {
      int r = c >> 2, cc = c & 3;
      uint4 v4 = (r < 65) ? *(const uint4*)(relb + r * 128 + ks * 32 + cc * 8)
                          : make_uint4(0, 0, 0, 0);
      *(uint4*)(&Bs[c * 8]) = v4;
    }
    __syncthreads();
    bf16x8 a = *(const bf16x8*)(&As[(w * 16 + lanelo) * 128 + ks * 32 + quad * 8]);
#pragma unroll
    for (int j = 0; j < 5; ++j) {
      bf16x8 bb = *(const bf16x8*)(&Bs[(j * 16 + lanelo) * 32 + quad * 8]);
      pacc[j] = MFMA16(a, bb, pacc[j]);
    }
    __syncthreads();
  }
#pragma unroll
  for (int j = 0; j < 5; ++j) {
    int col = j * 16 + lanelo;
#pragma unroll
    for (int i = 0; i < 4; ++i) Ps[(w * 16 + quad * 4 + i) * 80 + col] = pacc[j][i];
  }
  __syncthreads();

  // ---- QK: scores tile (64 x 512) ----
  f32x4 acc[32];
#pragma unroll
  for (int j = 0; j < 32; ++j) acc[j] = zf;
  for (int ks = 0; ks < 4; ++ks) {
    for (int c = tid; c < 2048; c += 256) {
      int r = c >> 2, cc = c & 3;
      *(uint4*)(&Bs[c * 8]) =
          *(const uint4*)(kbuf + ((size_t)bh * 512 + r) * 128 + ks * 32 + cc * 8);
    }
    __syncthreads();
    bf16x8 a = *(const bf16x8*)(&As[(w * 16 + lanelo) * 128 + ks * 32 + quad * 8]);
#pragma unroll
    for (int j = 0; j < 32; ++j) {
      bf16x8 bb = *(const bf16x8*)(&Bs[(j * 16 + lanelo) * 32 + quad * 8]);
      acc[j] = MFMA16(a, bb, acc[j]);
    }
    __syncthreads();
  }

  // ---- softmax (rows live across the 16 lanelo lanes of a quad) ----
  const float rscale = 0.08838834764831845f;  // 1/sqrt(128)
  float mrow[4] = {-1.0e30f, -1.0e30f, -1.0e30f, -1.0e30f};
#pragma unroll
  for (int j = 0; j < 32; ++j) {
    int k = j * 16 + lanelo;
    float cm = cmask[k];
#pragma unroll
    for (int i = 0; i < 4; ++i) {
      int row = w * 16 + quad * 4 + i;
      int qg = q0 + row;
      int d = k - qg;
      int r = min(max(d, -32), 32) + 32;
      float val = (acc[j][i] + Ps[row * 80 + r]) * rscale + cm;
      acc[j][i] = val;
      mrow[i] = fmaxf(mrow[i], val);
    }
  }
#pragma unroll
  for (int st = 1; st < 16; st <<= 1)
#pragma unroll
    for (int i = 0; i < 4; ++i) mrow[i] = fmaxf(mrow[i], __shfl_xor(mrow[i], st, 64));
  float srow[4] = {0.f, 0.f, 0.f, 0.f};
#pragma unroll
  for (int j = 0; j < 32; ++j)
#pragma unroll
    for (int i = 0; i < 4; ++i) {
      float e = __expf(acc[j][i] - mrow[i]);
      acc[j][i] = e;
      srow[i] += e;
    }
#pragma unroll
  for (int st = 1; st < 16; st <<= 1)
#pragma unroll
    for (int i = 0; i < 4; ++i) srow[i] += __shfl_xor(srow[i], st, 64);
  float rs[4];
#pragma unroll
  for (int i = 0; i < 4; ++i) rs[i] = (srow[i] > 0.f) ? 1.f / srow[i] : 0.f;

  // ---- write attn fp32 + buckets ----
  float s0a[4] = {0.f, 0.f, 0.f, 0.f}, s64a[4] = {0.f, 0.f, 0.f, 0.f};
#pragma unroll
  for (int j = 0; j < 32; ++j) {
    int k = j * 16 + lanelo;
#pragma unroll
    for (int i = 0; i < 4; ++i) {
      int row = w * 16 + quad * 4 + i;
      int qg = q0 + row;
      float at = acc[j][i] * rs[i];
      attn_out[((size_t)bh * 512 + qg) * 512 + k] = at;
      int d = k - qg;
      if (d <= -32) s0a[i] += at;
      else if (d >= 32) s64a[i] += at;
      else abuf[((size_t)bh * 512 + qg) * 96 + (d + 32)] = f2bf(at);
    }
  }
#pragma unroll
  for (int st = 1; st < 16; st <<= 1)
#pragma unroll
    for (int i = 0; i < 4; ++i) {
      s0a[i] += __shfl_xor(s0a[i], st, 64);
      s64a[i] += __shfl_xor(s64a[i], st, 64);
    }
  if (lanelo == 0) {
#pragma unroll
    for (int i = 0; i < 4; ++i) {
      int qg = q0 + w * 16 + quad * 4 + i;
      abuf[((size_t)bh * 512 + qg) * 96 + 0] = f2bf(s0a[i]);
      abuf[((size_t)bh * 512 + qg) * 96 + 64] = f2bf(s64a[i]);
    }
  }
}

// ---------------------------------------------------------------------------
// K6: ctx = attn @ v + a @ rel. MFMA. One block per (b,h,64-q tile).
// attn read fp32 (converted to bf16 during staging); buckets/vT/relT bf16.
// ---------------------------------------------------------------------------
__global__ __launch_bounds__(256) void av_ctx(
    const float* __restrict__ attn, const unsigned short* __restrict__ abuf,
    const unsigned short* __restrict__ vT, const unsigned short* __restrict__ relT,
    unsigned short* __restrict__ ctx) {
  __shared__ __align__(16) unsigned short As[64 * 32];
  __shared__ __align__(16) unsigned short Bs[128 * 32];
  const int idx = blockIdx.x;
  const int qt = idx & 7, bh = idx >> 3;
  const int q0 = qt * 64;
  const int tid = threadIdx.x, lane = tid & 63, w = tid >> 6;
  const int lanelo = lane & 15, quad = lane >> 4;
  const f32x4 zf = {0.f, 0.f, 0.f, 0.f};
  f32x4 acc[8];
#pragma unroll
  for (int j = 0; j < 8; ++j) acc[j] = zf;

  for (int kt = 0; kt < 19; ++kt) {
    {  // stage A (64x32): 256 chunks of 8
      int c = tid;
      int r = c >> 2, cc = c & 3;
      if (kt < 16) {
        const float* src = attn + ((size_t)bh * 512 + q0 + r) * 512 + kt * 32 + cc * 8;
        *(uint2*)(&As[c * 8]) = pack4(*(const float4*)(src));
        *(uint2*)(&As[c * 8 + 4]) = pack4(*(const float4*)(src + 4));
      } else {
        *(uint4*)(&As[c * 8]) =
            *(const uint4*)(abuf + ((size_t)bh * 512 + q0 + r) * 96 + (kt - 16) * 32 + cc * 8);
      }
    }
#pragma unroll
    for (int p = 0; p < 2; ++p) {  // stage B (128x32): 512 chunks of 8
      int c = p * 256 + tid;
      int r = c >> 2, cc = c & 3;
      uint4 vbv;
      if (kt < 16)
        vbv = *(const uint4*)(vT + ((size_t)bh * 128 + r) * 512 + kt * 32 + cc * 8);
      else
        vbv = *(const uint4*)(relT + r * 96 + (kt - 16) * 32 + cc * 8);
      *(uint4*)(&Bs[c * 8]) = vbv;
    }
    __syncthreads();
    bf16x8 a = *(const bf16x8*)(&As[(w * 16 + lanelo) * 32 + quad * 8]);
#pragma unroll
    for (int j = 0; j < 8; ++j) {
      bf16x8 bb = *(const bf16x8*)(&Bs[(j * 16 + lanelo) * 32 + quad * 8]);
      acc[j] = MFMA16(a, bb, acc[j]);
    }
    __syncthreads();
  }
  const int b = bh >> 3, h = bh & 7;
#pragma unroll
  for (int j = 0; j < 8; ++j) {
    int d = j * 16 + lanelo;
#pragma unroll
    for (int i = 0; i < 4; ++i) {
      int qg = q0 + w * 16 + quad * 4 + i;
      ctx[((size_t)(b * 512 + qg)) * 1024 + h * 128 + d] = f2bf(acc[j][i]);
    }
  }
}

// ---------------------------------------------------------------------------
// K7: out = ctx @ Wo^T + bo. MFMA 128x128 tiles; ctx bf16, Wo/bo/out fp32.
// ---------------------------------------------------------------------------
__global__ __launch_bounds__(256) void out_proj(
    const unsigned short* __restrict__ ctx, const float* __restrict__ Wo,
    const float* __restrict__ bo, float* __restrict__ outp) {
  __shared__ __align__(16) unsigned short As[128 * 64];
  __shared__ __align__(16) unsigned short Bs[128 * 64];
  const int bm = blockIdx.x & 31, bn = blockIdx.x >> 5;
  const int tid = threadIdx.x, lane = tid & 63, w = tid >> 6;
  const int wm = (w >> 1) * 64, wn = (w & 1) * 64;
  const int lanelo = lane & 15, quad = lane >> 4;
  const int row0 = bm * 128, col0 = bn * 128;
  f32x4 acc[4][4];
  const f32x4 zf = {0.f, 0.f, 0.f, 0.f};
#pragma unroll
  for (int i = 0; i < 4; ++i)
#pragma unroll
    for (int j = 0; j < 4; ++j) acc[i][j] = zf;

  for (int kt = 0; kt < 16; ++kt) {
#pragma unroll
    for (int p = 0; p < 4; ++p) {   // A: ctx bf16, 1024 chunks of 8
      int c = p * 256 + tid;
      int r = c >> 3, cc = c & 7;
      *(uint4*)(&As[c * 8]) = *(const uint4*)(ctx + (size_t)(row0 + r) * 1024 + kt * 64 + cc * 8);
    }
#pragma unroll
    for (int p = 0; p < 8; ++p) {   // B: Wo fp32 -> bf16, 2048 chunks of 4
      int c = p * 256 + tid;
      int r = c >> 4, cc = c & 15;
      *(uint2*)(&Bs[c * 4]) =
          pack4(*(const float4*)(Wo + (size_t)(col0 + r) * 1024 + kt * 64 + cc * 4));
    }
    __syncthreads();
#pragma unroll
    for (int ks = 0; ks < 2; ++ks) {
      bf16x8 a[4], bb[4];
#pragma unroll
      for (int i = 0; i < 4; ++i)
        a[i] = *(const bf16x8*)(&As[(wm + i * 16 + lanelo) * 64 + ks * 32 + quad * 8]);
#pragma unroll
      for (int j = 0; j < 4; ++j)
        bb[j] = *(const bf16x8*)(&Bs[(wn + j * 16 + lanelo) * 64 + ks * 32 + quad * 8]);
#pragma unroll
      for (int i = 0; i < 4; ++i)
#pragma unroll
        for (int j = 0; j < 4; ++j) acc[i][j] = MFMA16(a[i], bb[j], acc[i][j]);
    }
    __syncthreads();
  }
#pragma unroll
  for (int i = 0; i < 4; ++i) {
#pragma unroll
    for (int j = 0; j < 4; ++j) {
      int n = col0 + wn + j * 16 + lanelo;
      float bbv = bo[n];
#pragma unroll
      for (int r = 0; r < 4; ++r) {
        int m = row0 + wm + i * 16 + quad * 4 + r;
        outp[(size_t)m * 1024 + n] = acc[i][j][r] + bbv;
      }
    }
  }
}

// ---------------------------------------------------------------------------
extern "C" void kernel_launch(void* const* d_in, const int* in_sizes, int n_in,
                              void* d_out, int out_size, void* d_ws, size_t ws_size,
                              hipStream_t stream) {
  const float* x    = (const float*)d_in[0];
  const int*   mask = (const int*)d_in[1];
  const float* Wq   = (const float*)d_in[2];
  const float* bq   = (const float*)d_in[3];
  const float* Wk   = (const float*)d_in[4];
  const float* bk   = (const float*)d_in[5];
  const float* Wv   = (const float*)d_in[6];
  const float* bv   = (const float*)d_in[7];
  const float* Wo   = (const float*)d_in[8];
  const float* bo   = (const float*)d_in[9];
  const float* rel  = (const float*)d_in[10];
  const float* Wihf = (const float*)d_in[11];
  const float* Whhf = (const float*)d_in[12];
  const float* bihf = (const float*)d_in[13];
  const float* bhhf = (const float*)d_in[14];
  const float* Wihb = (const float*)d_in[15];
  const float* Whhb = (const float*)d_in[16];
  const float* bihb = (const float*)d_in[17];
  const float* bhhb = (const float*)d_in[18];

  // ws: 31,498,752 bytes used
  char* ws = (char*)d_ws;
  unsigned short* qb   = (unsigned short*)(ws + 0);          // 8,388,608 B
  unsigned short* kb   = (unsigned short*)(ws + 8388608);    // 8,388,608 B
  unsigned short* vT   = (unsigned short*)(ws + 16777216);   // 8,388,608 B
  unsigned short* abuf = (unsigned short*)(ws + 25165824);   // 6,291,456 B (32768x96)
  unsigned short* relb = (unsigned short*)(ws + 31457280);   //    16,640 B
  unsigned short* relT = (unsigned short*)(ws + 31474176);   //    24,576 B
  unsigned short* ctx  = qb;   // qb dead after scores_softmax

  float* outp  = (float*)d_out;
  float* attnF = outp + 4194304;                 // (B,H,S,S) fp32 = 67 MB
  // bf16 scratch inside the attn region; both dead before scores_softmax
  // overwrites the whole region with fp32 attn:
  unsigned short* vb     = (unsigned short*)attnF;             // 8.39 MB
  unsigned short* rnnout = (unsigned short*)attnF + 4194304;   // 12.58 MB

  qkv_proj<<<dim3(768), dim3(256), 0, stream>>>(x, Wq, bq, Wk, bk, Wv, bv, mask,
                                                qb, kb, vb, vT);
  prep_rel<<<dim3(48), dim3(256), 0, stream>>>(rel, relb, relT);
  rnn_fused<<<dim3(768), dim3(256), 0, stream>>>(qb, kb, vb, Wihf, Whhf, bihf, bhhf,
                                                 Wihb, Whhb, bihb, bhhb, rnnout);
  rnn_copyback<<<dim3(24576), dim3(256), 0, stream>>>(rnnout, qb, kb, vT);
  scores_softmax<<<dim3(512), dim3(256), 0, stream>>>(qb, kb, relb, mask, attnF, abuf);
  av_ctx<<<dim3(512), dim3(256), 0, stream>>>(attnF, abuf, vT, relT, ctx);
  out_proj<<<dim3(256), dim3(256), 0, stream>>>(ctx, Wo, bo, outp);
}

// Round 7
// 405.493 us; speedup vs baseline: 10.7606x; 1.0828x over previous
//
#include <hip/hip_runtime.h>

// ---------------------------------------------------------------------------
// MultiHeadedAttention w/ n-gram RNN heads + rel-pos embeddings. MFMA version.
// B=8 S=512 D=1024 H=8 DPH=128, MAX_REL=32, NG heads 4..7.
// I/O: float tensors FP32 (verified R5); mask int32. Internals bf16+MFMA.
// R7: all fp32->bf16 conversions hoisted into one prep pass; GEMMs stage
// pure bf16 (uint4). Conversions happen exactly once per element.
//
// ws (33,595,904 B): qb | kb | vT | abuf | relb | relT | Wob.  ctx aliases qb.
// d_out attn-region scratch (dead before scores overwrites with fp32 attn):
//   xb | vb | rnnout | Wqkvb | Wrnnb.
// ---------------------------------------------------------------------------

typedef __bf16 bf16x8 __attribute__((ext_vector_type(8)));
typedef float f32x4 __attribute__((ext_vector_type(4)));

#define MFMA16(a, b, c) __builtin_amdgcn_mfma_f32_16x16x32_bf16(a, b, c, 0, 0, 0)

__device__ __forceinline__ unsigned short f2bf(float f) {
  unsigned u = __float_as_uint(f);
  u += 0x7FFFu + ((u >> 16) & 1u);
  return (unsigned short)(u >> 16);
}
__device__ __forceinline__ uint2 pack4(float4 f) {
  uint2 r;
  r.x = (unsigned)f2bf(f.x) | ((unsigned)f2bf(f.y) << 16);
  r.y = (unsigned)f2bf(f.z) | ((unsigned)f2bf(f.w) << 16);
  return r;
}

// ---------------------------------------------------------------------------
// K0: one-shot fp32->bf16 conversion of x, Wq|Wk|Wv, Wo, RNN weights.
// Each thread converts one float4. Segment map over 2,113,536 float4s.
// ---------------------------------------------------------------------------
__global__ __launch_bounds__(256) void prep_bf16(
    const float* __restrict__ x,
    const float* __restrict__ Wq, const float* __restrict__ Wk,
    const float* __restrict__ Wv, const float* __restrict__ Wo,
    const float* __restrict__ Wihf, const float* __restrict__ Whhf,
    const float* __restrict__ Wihb, const float* __restrict__ Whhb,
    unsigned short* __restrict__ xb, unsigned short* __restrict__ Wqkvb,
    unsigned short* __restrict__ Wob, unsigned short* __restrict__ Wrnnb) {
  int i = blockIdx.x * 256 + threadIdx.x;   // float4 index
  const float* src;
  unsigned short* dst;
  int off;
  if (i < 1048576) {                    // x: 4,194,304 floats
    src = x; dst = xb; off = i;
  } else if (i < 1310720) {             // Wq
    src = Wq; dst = Wqkvb; off = i - 1048576;
  } else if (i < 1572864) {             // Wk
    src = Wk; dst = Wqkvb + 1048576; off = i - 1310720;
  } else if (i < 1835008) {             // Wv
    src = Wv; dst = Wqkvb + 2097152; off = i - 1572864;
  } else if (i < 2097152) {             // Wo
    src = Wo; dst = Wob; off = i - 1835008;
  } else if (i < 2101248) {             // Wihf
    src = Wihf; dst = Wrnnb; off = i - 2097152;
  } else if (i < 2105344) {             // Whhf
    src = Whhf; dst = Wrnnb + 16384; off = i - 2101248;
  } else if (i < 2109440) {             // Wihb
    src = Wihb; dst = Wrnnb + 32768; off = i - 2105344;
  } else {                              // Whhb
    src = Whhb; dst = Wrnnb + 49152; off = i - 2109440;
  }
  float4 f = *((const float4*)src + off);
  *(uint2*)(dst + (size_t)off * 4) = pack4(f);
}

// ---------------------------------------------------------------------------
// K1: QKV projection. GEMM (4096 x 3072virt x 1024), 128x128 tiles, MFMA.
// Pure bf16 staging (uint4). Epilogue: +bias(fp32), mask->0, scatter bf16
// to (B,H,S,128); v also transposed into vT.
// ---------------------------------------------------------------------------
__global__ __launch_bounds__(256) void qkv_proj(
    const unsigned short* __restrict__ xb, const unsigned short* __restrict__ Wqkvb,
    const float* __restrict__ bq, const float* __restrict__ bk,
    const float* __restrict__ bv, const int* __restrict__ mask,
    unsigned short* __restrict__ qb, unsigned short* __restrict__ kb,
    unsigned short* __restrict__ vb, unsigned short* __restrict__ vT) {
  __shared__ __align__(16) unsigned short As[128 * 64];
  __shared__ __align__(16) unsigned short Bs[128 * 64];
  const int bm = blockIdx.x & 31;
  const int bn = blockIdx.x >> 5;           // 0..23
  const int t = bn >> 3;                    // 0:q 1:k 2:v
  const int nloc0 = (bn & 7) * 128;
  const unsigned short* W = Wqkvb + (size_t)t * 1048576;
  const float* bias = (t == 0) ? bq : (t == 1) ? bk : bv;
  const int tid = threadIdx.x;
  const int lane = tid & 63, w = tid >> 6;
  const int wm = (w >> 1) * 64, wn = (w & 1) * 64;
  const int lanelo = lane & 15, quad = lane >> 4;
  const int row0 = bm * 128;

  f32x4 acc[4][4];
  const f32x4 zf = {0.f, 0.f, 0.f, 0.f};
#pragma unroll
  for (int i = 0; i < 4; ++i)
#pragma unroll
    for (int j = 0; j < 4; ++j) acc[i][j] = zf;

  for (int kt = 0; kt < 16; ++kt) {
#pragma unroll
    for (int p = 0; p < 4; ++p) {
      int c = p * 256 + tid;          // 1024 chunks of 8 bf16 per buffer
      int r = c >> 3, cc = c & 7;
      *(uint4*)(&As[c * 8]) = *(const uint4*)(xb + (size_t)(row0 + r) * 1024 + kt * 64 + cc * 8);
      *(uint4*)(&Bs[c * 8]) = *(const uint4*)(W + (size_t)(nloc0 + r) * 1024 + kt * 64 + cc * 8);
    }
    __syncthreads();
#pragma unroll
    for (int ks = 0; ks < 2; ++ks) {
      bf16x8 a[4], bb[4];
#pragma unroll
      for (int i = 0; i < 4; ++i)
        a[i] = *(const bf16x8*)(&As[(wm + i * 16 + lanelo) * 64 + ks * 32 + quad * 8]);
#pragma unroll
      for (int j = 0; j < 4; ++j)
        bb[j] = *(const bf16x8*)(&Bs[(wn + j * 16 + lanelo) * 64 + ks * 32 + quad * 8]);
#pragma unroll
      for (int i = 0; i < 4; ++i)
#pragma unroll
        for (int j = 0; j < 4; ++j) acc[i][j] = MFMA16(a[i], bb[j], acc[i][j]);
    }
    __syncthreads();
  }
#pragma unroll
  for (int i = 0; i < 4; ++i) {
#pragma unroll
    for (int j = 0; j < 4; ++j) {
      int jj = nloc0 + wn + j * 16 + lanelo;   // 0..1023 within tensor
      int hh = jj >> 7, dc = jj & 127;
      float bvv = bias[jj];
#pragma unroll
      for (int r = 0; r < 4; ++r) {
        int m = row0 + wm + i * 16 + quad * 4 + r;
        int b = m >> 9, s = m & 511;
        float val = acc[i][j][r] + bvv;
        if (mask[b * 512 + s]) val = 0.f;
        unsigned short o = f2bf(val);
        size_t off = ((size_t)(b * 8 + hh) * 512 + s) * 128 + dc;
        if (t == 0) qb[off] = o;
        else if (t == 1) kb[off] = o;
        else {
          vb[off] = o;
          vT[((size_t)(b * 8 + hh) * 128 + dc) * 512 + s] = o;
        }
      }
    }
  }
}

// ---------------------------------------------------------------------------
// K2: rel prep: relb (65x128 bf16 row-major), relT (128x96 bf16, zero-pad).
// ---------------------------------------------------------------------------
__global__ __launch_bounds__(256) void prep_rel(
    const float* __restrict__ rel, unsigned short* __restrict__ relb,
    unsigned short* __restrict__ relT) {
  int i = blockIdx.x * 256 + threadIdx.x;
  if (i < 65 * 128) relb[i] = f2bf(rel[i]);
  if (i < 128 * 96) {
    int d = i / 96, r = i - d * 96;
    relT[i] = (r < 65) ? f2bf(rel[r * 128 + d]) : (unsigned short)0;
  }
}

// ---------------------------------------------------------------------------
// K3: fused bidirectional 2-step RNN on heads 4..7 of q,k,v. MFMA.
// grid 768 = 96 groups x 8 tiles of 64 positions. Weights pre-converted bf16.
// ---------------------------------------------------------------------------
__global__ __launch_bounds__(256) void rnn_fused(
    const unsigned short* __restrict__ qb, const unsigned short* __restrict__ kb,
    const unsigned short* __restrict__ vb,
    const unsigned short* __restrict__ Wrnnb,
    const float* __restrict__ bihf, const float* __restrict__ bhhf,
    const float* __restrict__ bihb, const float* __restrict__ bhhb,
    unsigned short* __restrict__ rnn_out) {
  __shared__ __align__(16) unsigned short X[65 * 128];   // rows s0-1 .. s0+63
  __shared__ __align__(16) unsigned short Wi[128 * 128];
  __shared__ __align__(16) unsigned short Wh[128 * 128];
  __shared__ __align__(16) unsigned short H1[64 * 128];
  __shared__ float cbf[128], cbb[128];

  const unsigned short* Wihfb = Wrnnb;
  const unsigned short* Whhfb = Wrnnb + 16384;
  const unsigned short* Wihbb = Wrnnb + 32768;
  const unsigned short* Whhbb = Wrnnb + 49152;

  const int gid = blockIdx.x;
  const int tile = gid & 7;
  const int g = gid >> 3;              // 0..95
  const int t = g >> 5;
  const int rem = g & 31;
  const int b = rem >> 2, h = (rem & 3) + 4;
  const int s0 = tile * 64;
  const unsigned short* src = (t == 0) ? qb : (t == 1) ? kb : vb;
  const size_t rowbase = (size_t)(b * 8 + h) * 512;
  const int tid = threadIdx.x;

  for (int c = tid; c < 65 * 16; c += 256) {   // X: 65 rows x 16 uint4
    int r = c >> 4, cc = c & 15;
    uint4 v4;
    if (r == 0 && s0 == 0) v4 = make_uint4(0, 0, 0, 0);
    else v4 = *(const uint4*)(src + (rowbase + (s0 - 1 + r)) * 128 + cc * 8);
    *(uint4*)(&X[c * 8]) = v4;
  }
#pragma unroll
  for (int p = 0; p < 8; ++p) {       // weights: 2048 chunks of 8 bf16 each
    int c = p * 256 + tid;
    *(uint4*)(&Wi[c * 8]) = *(const uint4*)(Wihfb + c * 8);
    *(uint4*)(&Wh[c * 8]) = *(const uint4*)(Whhfb + c * 8);
  }
  if (tid < 128) {
    cbf[tid] = bihf[tid] + bhhf[tid];
    cbb[tid] = bihb[tid] + bhhb[tid];
  }
  __syncthreads();

  const int lane = tid & 63, w = tid >> 6;
  const int lanelo = lane & 15, quad = lane >> 4;
  const int marow = w * 16 + lanelo;
  const f32x4 zf = {0.f, 0.f, 0.f, 0.f};

  // ---- forward h1 = tanh(Wihf x_{s-1} + cbf) ----
  f32x4 g1[8];
#pragma unroll
  for (int j = 0; j < 8; ++j) g1[j] = zf;
#pragma unroll
  for (int ks = 0; ks < 4; ++ks) {
    bf16x8 a = *(const bf16x8*)(&X[marow * 128 + ks * 32 + quad * 8]);
#pragma unroll
    for (int j = 0; j < 8; ++j) {
      bf16x8 bb = *(const bf16x8*)(&Wi[(j * 16 + lanelo) * 128 + ks * 32 + quad * 8]);
      g1[j] = MFMA16(a, bb, g1[j]);
    }
  }
#pragma unroll
  for (int j = 0; j < 8; ++j) {
    int col = j * 16 + lanelo;
    float cb = cbf[col];
#pragma unroll
    for (int i = 0; i < 4; ++i) {
      int row = w * 16 + quad * 4 + i;
      H1[row * 128 + col] = f2bf(tanhf(g1[j][i] + cb));
    }
  }
  __syncthreads();
  // ---- forward out = tanh(Wihf x_s + Whhf h1 + cbf) ----
  f32x4 a2[8];
#pragma unroll
  for (int j = 0; j < 8; ++j) a2[j] = zf;
#pragma unroll
  for (int ks = 0; ks < 4; ++ks) {
    bf16x8 a = *(const bf16x8*)(&X[(marow + 1) * 128 + ks * 32 + quad * 8]);
#pragma unroll
    for (int j = 0; j < 8; ++j) {
      bf16x8 bb = *(const bf16x8*)(&Wi[(j * 16 + lanelo) * 128 + ks * 32 + quad * 8]);
      a2[j] = MFMA16(a, bb, a2[j]);
    }
  }
#pragma unroll
  for (int ks = 0; ks < 4; ++ks) {
    bf16x8 a = *(const bf16x8*)(&H1[marow * 128 + ks * 32 + quad * 8]);
#pragma unroll
    for (int j = 0; j < 8; ++j) {
      bf16x8 bb = *(const bf16x8*)(&Wh[(j * 16 + lanelo) * 128 + ks * 32 + quad * 8]);
      a2[j] = MFMA16(a, bb, a2[j]);
    }
  }
  float outF[8][4];
#pragma unroll
  for (int j = 0; j < 8; ++j) {
    int col = j * 16 + lanelo;
    float cb = cbf[col];
#pragma unroll
    for (int i = 0; i < 4; ++i) outF[j][i] = tanhf(a2[j][i] + cb);
  }
  __syncthreads();
#pragma unroll
  for (int p = 0; p < 8; ++p) {   // restage backward weights
    int c = p * 256 + tid;
    *(uint4*)(&Wi[c * 8]) = *(const uint4*)(Wihbb + c * 8);
    *(uint4*)(&Wh[c * 8]) = *(const uint4*)(Whhbb + c * 8);
  }
  __syncthreads();
  // ---- backward h1b = tanh(Wihb x_s + cbb) ----
#pragma unroll
  for (int j = 0; j < 8; ++j) g1[j] = zf;
#pragma unroll
  for (int ks = 0; ks < 4; ++ks) {
    bf16x8 a = *(const bf16x8*)(&X[(marow + 1) * 128 + ks * 32 + quad * 8]);
#pragma unroll
    for (int j = 0; j < 8; ++j) {
      bf16x8 bb = *(const bf16x8*)(&Wi[(j * 16 + lanelo) * 128 + ks * 32 + quad * 8]);
      g1[j] = MFMA16(a, bb, g1[j]);
    }
  }
#pragma unroll
  for (int j = 0; j < 8; ++j) {
    int col = j * 16 + lanelo;
    float cb = cbb[col];
#pragma unroll
    for (int i = 0; i < 4; ++i) {
      int row = w * 16 + quad * 4 + i;
      H1[row * 128 + col] = f2bf(tanhf(g1[j][i] + cb));
    }
  }
  __syncthreads();
  // ---- backward out + combine + store ----
#pragma unroll
  for (int j = 0; j < 8; ++j) a2[j] = zf;
#pragma unroll
  for (int ks = 0; ks < 4; ++ks) {
    bf16x8 a = *(const bf16x8*)(&X[marow * 128 + ks * 32 + quad * 8]);
#pragma unroll
    for (int j = 0; j < 8; ++j) {
      bf16x8 bb = *(const bf16x8*)(&Wi[(j * 16 + lanelo) * 128 + ks * 32 + quad * 8]);
      a2[j] = MFMA16(a, bb, a2[j]);
    }
  }
#pragma unroll
  for (int ks = 0; ks < 4; ++ks) {
    bf16x8 a = *(const bf16x8*)(&H1[marow * 128 + ks * 32 + quad * 8]);
#pragma unroll
    for (int j = 0; j < 8; ++j) {
      bf16x8 bb = *(const bf16x8*)(&Wh[(j * 16 + lanelo) * 128 + ks * 32 + quad * 8]);
      a2[j] = MFMA16(a, bb, a2[j]);
    }
  }
#pragma unroll
  for (int j = 0; j < 8; ++j) {
    int col = j * 16 + lanelo;
    float cb = cbb[col];
#pragma unroll
    for (int i = 0; i < 4; ++i) {
      int row = w * 16 + quad * 4 + i;
      float val = outF[j][i] + tanhf(a2[j][i] + cb);
      rnn_out[((size_t)g * 512 + s0 + row) * 128 + col] = f2bf(val);
    }
  }
}

// ---------------------------------------------------------------------------
// K4: copy rnn results back into qb/kb (+vT for v).
// ---------------------------------------------------------------------------
__global__ __launch_bounds__(256) void rnn_copyback(
    const unsigned short* __restrict__ rnn_out,
    unsigned short* __restrict__ qb, unsigned short* __restrict__ kb,
    unsigned short* __restrict__ vT) {
  int idx = blockIdx.x * 256 + threadIdx.x;   // 6,291,456
  int g = idx >> 16;
  int r2 = idx & 65535;
  int s = r2 >> 7, col = r2 & 127;
  int t = g >> 5, rem = g & 31, b = rem >> 2, h = (rem & 3) + 4;
  unsigned short val = rnn_out[idx];
  size_t off = ((size_t)(b * 8 + h) * 512 + s) * 128 + col;
  if (t == 0) qb[off] = val;
  else if (t == 1) kb[off] = val;
  else vT[((size_t)(b * 8 + h) * 128 + col) * 512 + s] = val;
}

// ---------------------------------------------------------------------------
// K5: scores + softmax + bucket sums. MFMA. One block per (b,h,64-q tile).
// attn written fp32 to d_out; buckets bf16 (stride 96, cols 65..95 zeroed).
// ---------------------------------------------------------------------------
__global__ __launch_bounds__(256) void scores_softmax(
    const unsigned short* __restrict__ qbuf, const unsigned short* __restrict__ kbuf,
    const unsigned short* __restrict__ relb, const int* __restrict__ mask,
    float* __restrict__ attn_out, unsigned short* __restrict__ abuf) {
  __shared__ __align__(16) unsigned short As[64 * 128];
  __shared__ __align__(16) unsigned short Bs[512 * 32];
  __shared__ float Ps[64 * 80];
  __shared__ float cmask[512];
  const int idx = blockIdx.x;
  const int qt = idx & 7, bh = idx >> 3, b = bh >> 3;
  const int q0 = qt * 64;
  const size_t qrow0 = (size_t)bh * 512 + q0;
  const int tid = threadIdx.x;

  for (int i = tid; i < 64 * 96; i += 256) abuf[qrow0 * 96 + i] = 0;
  for (int c = tid; c < 1024; c += 256) {
    int r = c >> 4, cc = c & 15;
    *(uint4*)(&As[c * 8]) = *(const uint4*)(qbuf + (qrow0 + r) * 128 + cc * 8);
  }
  for (int i = tid; i < 512; i += 256) cmask[i] = mask[b * 512 + i] ? -1e9f : 0.f;
  __syncthreads();

  const int lane = tid & 63, w = tid >> 6;
  const int lanelo = lane & 15, quad = lane >> 4;
  const f32x4 zf = {0.f, 0.f, 0.f, 0.f};

  // ---- P: p[q][r] = q . rel[r], r<65 (pad to 80) ----
  f32x4 pacc[5];
#pragma unroll
  for (int j = 0; j < 5; ++j) pacc[j] = zf;
  for (int ks = 0; ks < 4; ++ks) {
    for (int c = tid; c < 320; c += 256) {
      int r = c >> 2, cc = c & 3;
      uint4 v4 = (r < 65) ? *(const uint4*)(relb + r * 128 + ks * 32 + cc * 8)
                          : make_uint4(0, 0, 0, 0);
      *(uint4*)(&Bs[c * 8]) = v4;
    }
    __syncthreads();
    bf16x8 a = *(const bf16x8*)(&As[(w * 16 + lanelo) * 128 + ks * 32 + quad * 8]);
#pragma unroll
    for (int j = 0; j < 5; ++j) {
      bf16x8 bb = *(const bf16x8*)(&Bs[(j * 16 + lanelo) * 32 + quad * 8]);
      pacc[j] = MFMA16(a, bb, pacc[j]);
    }
    __syncthreads();
  }
#pragma unroll
  for (int j = 0; j < 5; ++j) {
    int col = j * 16 + lanelo;
#pragma unroll
    for (int i = 0; i < 4; ++i) Ps[(w * 16 + quad * 4 + i) * 80 + col] = pacc[j][i];
  }
  __syncthreads();

  // ---- QK: scores tile (64 x 512) ----
  f32x4 acc[32];
#pragma unroll
  for (int j = 0; j < 32; ++j) acc[j] = zf;
  for (int ks = 0; ks < 4; ++ks) {
    for (int c = tid; c < 2048; c += 256) {
      int r = c >> 2, cc = c & 3;
      *(uint4*)(&Bs[c * 8]) =
          *(const uint4*)(kbuf + ((size_t)bh * 512 + r) * 128 + ks * 32 + cc * 8);
    }
    __syncthreads();
    bf16x8 a = *(const bf16x8*)(&As[(w * 16 + lanelo) * 128 + ks * 32 + quad * 8]);
#pragma unroll
    for (int j = 0; j < 32; ++j) {
      bf16x8 bb = *(const bf16x8*)(&Bs[(j * 16 + lanelo) * 32 + quad * 8]);
      acc[j] = MFMA16(a, bb, acc[j]);
    }
    __syncthreads();
  }

  // ---- softmax (rows live across the 16 lanelo lanes of a quad) ----
  const float rscale = 0.08838834764831845f;  // 1/sqrt(128)
  float mrow[4] = {-1.0e30f, -1.0e30f, -1.0e30f, -1.0e30f};
#pragma unroll
  for (int j = 0; j < 32; ++j) {
    int k = j * 16 + lanelo;
    float cm = cmask[k];
#pragma unroll
    for (int i = 0; i < 4; ++i) {
      int row = w * 16 + quad * 4 + i;
      int qg = q0 + row;
      int d = k - qg;
      int r = min(max(d, -32), 32) + 32;
      float val = (acc[j][i] + Ps[row * 80 + r]) * rscale + cm;
      acc[j][i] = val;
      mrow[i] = fmaxf(mrow[i], val);
    }
  }
#pragma unroll
  for (int st = 1; st < 16; st <<= 1)
#pragma unroll
    for (int i = 0; i < 4; ++i) mrow[i] = fmaxf(mrow[i], __shfl_xor(mrow[i], st, 64));
  float srow[4] = {0.f, 0.f, 0.f, 0.f};
#pragma unroll
  for (int j = 0; j < 32; ++j)
#pragma unroll
    for (int i = 0; i < 4; ++i) {
      float e = __expf(acc[j][i] - mrow[i]);
      acc[j][i] = e;
      srow[i] += e;
    }
#pragma unroll
  for (int st = 1; st < 16; st <<= 1)
#pragma unroll
    for (int i = 0; i < 4; ++i) srow[i] += __shfl_xor(srow[i], st, 64);
  float rs[4];
#pragma unroll
  for (int i = 0; i < 4; ++i) rs[i] = (srow[i] > 0.f) ? 1.f / srow[i] : 0.f;

  // ---- write attn fp32 + buckets ----
  float s0a[4] = {0.f, 0.f, 0.f, 0.f}, s64a[4] = {0.f, 0.f, 0.f, 0.f};
#pragma unroll
  for (int j = 0; j < 32; ++j) {
    int k = j * 16 + lanelo;
#pragma unroll
    for (int i = 0; i < 4; ++i) {
      int row = w * 16 + quad * 4 + i;
      int qg = q0 + row;
      float at = acc[j][i] * rs[i];
      attn_out[((size_t)bh * 512 + qg) * 512 + k] = at;
      int d = k - qg;
      if (d <= -32) s0a[i] += at;
      else if (d >= 32) s64a[i] += at;
      else abuf[((size_t)bh * 512 + qg) * 96 + (d + 32)] = f2bf(at);
    }
  }
#pragma unroll
  for (int st = 1; st < 16; st <<= 1)
#pragma unroll
    for (int i = 0; i < 4; ++i) {
      s0a[i] += __shfl_xor(s0a[i], st, 64);
      s64a[i] += __shfl_xor(s64a[i], st, 64);
    }
  if (lanelo == 0) {
#pragma unroll
    for (int i = 0; i < 4; ++i) {
      int qg = q0 + w * 16 + quad * 4 + i;
      abuf[((size_t)bh * 512 + qg) * 96 + 0] = f2bf(s0a[i]);
      abuf[((size_t)bh * 512 + qg) * 96 + 64] = f2bf(s64a[i]);
    }
  }
}

// ---------------------------------------------------------------------------
// K6: ctx = attn @ v + a @ rel. MFMA. One block per (b,h,64-q tile).
// attn read fp32 (converted to bf16 during staging); buckets/vT/relT bf16.
// ---------------------------------------------------------------------------
__global__ __launch_bounds__(256) void av_ctx(
    const float* __restrict__ attn, const unsigned short* __restrict__ abuf,
    const unsigned short* __restrict__ vT, const unsigned short* __restrict__ relT,
    unsigned short* __restrict__ ctx) {
  __shared__ __align__(16) unsigned short As[64 * 32];
  __shared__ __align__(16) unsigned short Bs[128 * 32];
  const int idx = blockIdx.x;
  const int qt = idx & 7, bh = idx >> 3;
  const int q0 = qt * 64;
  const int tid = threadIdx.x, lane = tid & 63, w = tid >> 6;
  const int lanelo = lane & 15, quad = lane >> 4;
  const f32x4 zf = {0.f, 0.f, 0.f, 0.f};
  f32x4 acc[8];
#pragma unroll
  for (int j = 0; j < 8; ++j) acc[j] = zf;

  for (int kt = 0; kt < 19; ++kt) {
    {  // stage A (64x32): 256 chunks of 8
      int c = tid;
      int r = c >> 2, cc = c & 3;
      if (kt < 16) {
        const float* src = attn + ((size_t)bh * 512 + q0 + r) * 512 + kt * 32 + cc * 8;
        *(uint2*)(&As[c * 8]) = pack4(*(const float4*)(src));
        *(uint2*)(&As[c * 8 + 4]) = pack4(*(const float4*)(src + 4));
      } else {
        *(uint4*)(&As[c * 8]) =
            *(const uint4*)(abuf + ((size_t)bh * 512 + q0 + r) * 96 + (kt - 16) * 32 + cc * 8);
      }
    }
#pragma unroll
    for (int p = 0; p < 2; ++p) {  // stage B (128x32): 512 chunks of 8
      int c = p * 256 + tid;
      int r = c >> 2, cc = c & 3;
      uint4 vbv;
      if (kt < 16)
        vbv = *(const uint4*)(vT + ((size_t)bh * 128 + r) * 512 + kt * 32 + cc * 8);
      else
        vbv = *(const uint4*)(relT + r * 96 + (kt - 16) * 32 + cc * 8);
      *(uint4*)(&Bs[c * 8]) = vbv;
    }
    __syncthreads();
    bf16x8 a = *(const bf16x8*)(&As[(w * 16 + lanelo) * 32 + quad * 8]);
#pragma unroll
    for (int j = 0; j < 8; ++j) {
      bf16x8 bb = *(const bf16x8*)(&Bs[(j * 16 + lanelo) * 32 + quad * 8]);
      acc[j] = MFMA16(a, bb, acc[j]);
    }
    __syncthreads();
  }
  const int b = bh >> 3, h = bh & 7;
#pragma unroll
  for (int j = 0; j < 8; ++j) {
    int d = j * 16 + lanelo;
#pragma unroll
    for (int i = 0; i < 4; ++i) {
      int qg = q0 + w * 16 + quad * 4 + i;
      ctx[((size_t)(b * 512 + qg)) * 1024 + h * 128 + d] = f2bf(acc[j][i]);
    }
  }
}

// ---------------------------------------------------------------------------
// K7: out = ctx @ Wo^T + bo. MFMA 128x128 tiles; ctx/Wob bf16, bo/out fp32.
// ---------------------------------------------------------------------------
__global__ __launch_bounds__(256) void out_proj(
    const unsigned short* __restrict__ ctx, const unsigned short* __restrict__ Wob,
    const float* __restrict__ bo, float* __restrict__ outp) {
  __shared__ __align__(16) unsigned short As[128 * 64];
  __shared__ __align__(16) unsigned short Bs[128 * 64];
  const int bm = blockIdx.x & 31, bn = blockIdx.x >> 5;
  const int tid = threadIdx.x, lane = tid & 63, w = tid >> 6;
  const int wm = (w >> 1) * 64, wn = (w & 1) * 64;
  const int lanelo = lane & 15, quad = lane >> 4;
  const int row0 = bm * 128, col0 = bn * 128;
  f32x4 acc[4][4];
  const f32x4 zf = {0.f, 0.f, 0.f, 0.f};
#pragma unroll
  for (int i = 0; i < 4; ++i)
#pragma unroll
    for (int j = 0; j < 4; ++j) acc[i][j] = zf;

  for (int kt = 0; kt < 16; ++kt) {
#pragma unroll
    for (int p = 0; p < 4; ++p) {
      int c = p * 256 + tid;
      int r = c >> 3, cc = c & 7;
      *(uint4*)(&As[c * 8]) = *(const uint4*)(ctx + (size_t)(row0 + r) * 1024 + kt * 64 + cc * 8);
      *(uint4*)(&Bs[c * 8]) = *(const uint4*)(Wob + (size_t)(col0 + r) * 1024 + kt * 64 + cc * 8);
    }
    __syncthreads();
#pragma unroll
    for (int ks = 0; ks < 2; ++ks) {
      bf16x8 a[4], bb[4];
#pragma unroll
      for (int i = 0; i < 4; ++i)
        a[i] = *(const bf16x8*)(&As[(wm + i * 16 + lanelo) * 64 + ks * 32 + quad * 8]);
#pragma unroll
      for (int j = 0; j < 4; ++j)
        bb[j] = *(const bf16x8*)(&Bs[(wn + j * 16 + lanelo) * 64 + ks * 32 + quad * 8]);
#pragma unroll
      for (int i = 0; i < 4; ++i)
#pragma unroll
        for (int j = 0; j < 4; ++j) acc[i][j] = MFMA16(a[i], bb[j], acc[i][j]);
    }
    __syncthreads();
  }
#pragma unroll
  for (int i = 0; i < 4; ++i) {
#pragma unroll
    for (int j = 0; j < 4; ++j) {
      int n = col0 + wn + j * 16 + lanelo;
      float bbv = bo[n];
#pragma unroll
      for (int r = 0; r < 4; ++r) {
        int m = row0 + wm + i * 16 + quad * 4 + r;
        outp[(size_t)m * 1024 + n] = acc[i][j][r] + bbv;
      }
    }
  }
}

// ---------------------------------------------------------------------------
extern "C" void kernel_launch(void* const* d_in, const int* in_sizes, int n_in,
                              void* d_out, int out_size, void* d_ws, size_t ws_size,
                              hipStream_t stream) {
  const float* x    = (const float*)d_in[0];
  const int*   mask = (const int*)d_in[1];
  const float* Wq   = (const float*)d_in[2];
  const float* bq   = (const float*)d_in[3];
  const float* Wk   = (const float*)d_in[4];
  const float* bk   = (const float*)d_in[5];
  const float* Wv   = (const float*)d_in[6];
  const float* bv   = (const float*)d_in[7];
  const float* Wo   = (const float*)d_in[8];
  const float* bo   = (const float*)d_in[9];
  const float* rel  = (const float*)d_in[10];
  const float* Wihf = (const float*)d_in[11];
  const float* Whhf = (const float*)d_in[12];
  const float* bihf = (const float*)d_in[13];
  const float* bhhf = (const float*)d_in[14];
  const float* Wihb = (const float*)d_in[15];
  const float* Whhb = (const float*)d_in[16];
  const float* bihb = (const float*)d_in[17];
  const float* bhhb = (const float*)d_in[18];

  // ws: 33,595,904 bytes used (proven-safe <= 33,702,144)
  char* ws = (char*)d_ws;
  unsigned short* qb   = (unsigned short*)(ws + 0);          // 8,388,608 B
  unsigned short* kb   = (unsigned short*)(ws + 8388608);    // 8,388,608 B
  unsigned short* vT   = (unsigned short*)(ws + 16777216);   // 8,388,608 B
  unsigned short* abuf = (unsigned short*)(ws + 25165824);   // 6,291,456 B (32768x96)
  unsigned short* relb = (unsigned short*)(ws + 31457280);   //    16,640 B
  unsigned short* relT = (unsigned short*)(ws + 31473920);   //    24,576 B
  unsigned short* Wob  = (unsigned short*)(ws + 31498496);   // 2,097,152 B
  unsigned short* ctx  = qb;   // qb dead after scores_softmax

  float* outp  = (float*)d_out;
  float* attnF = outp + 4194304;                 // (B,H,S,S) fp32 = 67.1 MB
  // bf16 scratch inside the attn region; all dead before scores_softmax
  // overwrites the whole region with fp32 attn:
  unsigned short* abase  = (unsigned short*)attnF;
  unsigned short* xb     = abase;                 // 4,194,304 elems
  unsigned short* vb     = abase + 4194304;       // 4,194,304 elems
  unsigned short* rnnout = abase + 8388608;       // 6,291,456 elems
  unsigned short* Wqkvb  = abase + 14680064;      // 3,145,728 elems
  unsigned short* Wrnnb  = abase + 17825792;      //    65,536 elems

  prep_bf16<<<dim3(8256), dim3(256), 0, stream>>>(
      x, Wq, Wk, Wv, Wo, Wihf, Whhf, Wihb, Whhb, xb, Wqkvb, Wob, Wrnnb);
  prep_rel<<<dim3(48), dim3(256), 0, stream>>>(rel, relb, relT);
  qkv_proj<<<dim3(768), dim3(256), 0, stream>>>(xb, Wqkvb, bq, bk, bv, mask,
                                                qb, kb, vb, vT);
  rnn_fused<<<dim3(768), dim3(256), 0, stream>>>(qb, kb, vb, Wrnnb,
                                                 bihf, bhhf, bihb, bhhb, rnnout);
  rnn_copyback<<<dim3(24576), dim3(256), 0, stream>>>(rnnout, qb, kb, vT);
  scores_softmax<<<dim3(512), dim3(256), 0, stream>>>(qb, kb, relb, mask, attnF, abuf);
  av_ctx<<<dim3(512), dim3(256), 0, stream>>>(attnF, abuf, vT, relT, ctx);
  out_proj<<<dim3(256), dim3(256), 0, stream>>>(ctx, Wob, bo, outp);
}

// Round 8
// 373.382 us; speedup vs baseline: 11.6860x; 1.0860x over previous
//
#include <hip/hip_runtime.h>

// ---------------------------------------------------------------------------
// MultiHeadedAttention w/ n-gram RNN heads + rel-pos embeddings. MFMA version.
// B=8 S=512 D=1024 H=8 DPH=128, MAX_REL=32, NG heads 4..7.
// I/O: float tensors FP32 (verified R5); mask int32. Internals bf16+MFMA.
// R8: LDS leading-dim padding everywhere (128->136, 64->72, 32->40 elems)
// to kill the 16-way bank conflicts (stride ≡ 0 mod 32 words) seen in R7
// (SQ_LDS_BANK_CONFLICT 1.9e7 in rnn_fused, 9.4e6 in qkv_proj).
//
// ws (33,595,904 B): qb | kb | vT | abuf | relb | relT | Wob.  ctx aliases qb.
// d_out attn-region scratch (dead before scores overwrites with fp32 attn):
//   xb | vb | rnnout | Wqkvb | Wrnnb.
// ---------------------------------------------------------------------------

typedef __bf16 bf16x8 __attribute__((ext_vector_type(8)));
typedef float f32x4 __attribute__((ext_vector_type(4)));

#define MFMA16(a, b, c) __builtin_amdgcn_mfma_f32_16x16x32_bf16(a, b, c, 0, 0, 0)

__device__ __forceinline__ unsigned short f2bf(float f) {
  unsigned u = __float_as_uint(f);
  u += 0x7FFFu + ((u >> 16) & 1u);
  return (unsigned short)(u >> 16);
}
__device__ __forceinline__ uint2 pack4(float4 f) {
  uint2 r;
  r.x = (unsigned)f2bf(f.x) | ((unsigned)f2bf(f.y) << 16);
  r.y = (unsigned)f2bf(f.z) | ((unsigned)f2bf(f.w) << 16);
  return r;
}

// ---------------------------------------------------------------------------
// K0: one-shot fp32->bf16 conversion of x, Wq|Wk|Wv, Wo, RNN weights.
// ---------------------------------------------------------------------------
__global__ __launch_bounds__(256) void prep_bf16(
    const float* __restrict__ x,
    const float* __restrict__ Wq, const float* __restrict__ Wk,
    const float* __restrict__ Wv, const float* __restrict__ Wo,
    const float* __restrict__ Wihf, const float* __restrict__ Whhf,
    const float* __restrict__ Wihb, const float* __restrict__ Whhb,
    unsigned short* __restrict__ xb, unsigned short* __restrict__ Wqkvb,
    unsigned short* __restrict__ Wob, unsigned short* __restrict__ Wrnnb) {
  int i = blockIdx.x * 256 + threadIdx.x;   // float4 index
  const float* src;
  unsigned short* dst;
  int off;
  if (i < 1048576) {                    // x
    src = x; dst = xb; off = i;
  } else if (i < 1310720) {             // Wq
    src = Wq; dst = Wqkvb; off = i - 1048576;
  } else if (i < 1572864) {             // Wk
    src = Wk; dst = Wqkvb + 1048576; off = i - 1310720;
  } else if (i < 1835008) {             // Wv
    src = Wv; dst = Wqkvb + 2097152; off = i - 1572864;
  } else if (i < 2097152) {             // Wo
    src = Wo; dst = Wob; off = i - 1835008;
  } else if (i < 2101248) {             // Wihf
    src = Wihf; dst = Wrnnb; off = i - 2097152;
  } else if (i < 2105344) {             // Whhf
    src = Whhf; dst = Wrnnb + 16384; off = i - 2101248;
  } else if (i < 2109440) {             // Wihb
    src = Wihb; dst = Wrnnb + 32768; off = i - 2105344;
  } else {                              // Whhb
    src = Whhb; dst = Wrnnb + 49152; off = i - 2109440;
  }
  float4 f = *((const float4*)src + off);
  *(uint2*)(dst + (size_t)off * 4) = pack4(f);
}

// ---------------------------------------------------------------------------
// K1: QKV projection. GEMM 128x128 tiles, MFMA. LDS rows padded 64->72.
// ---------------------------------------------------------------------------
__global__ __launch_bounds__(256) void qkv_proj(
    const unsigned short* __restrict__ xb, const unsigned short* __restrict__ Wqkvb,
    const float* __restrict__ bq, const float* __restrict__ bk,
    const float* __restrict__ bv, const int* __restrict__ mask,
    unsigned short* __restrict__ qb, unsigned short* __restrict__ kb,
    unsigned short* __restrict__ vb, unsigned short* __restrict__ vT) {
  __shared__ __align__(16) unsigned short As[128 * 72];
  __shared__ __align__(16) unsigned short Bs[128 * 72];
  const int bm = blockIdx.x & 31;
  const int bn = blockIdx.x >> 5;           // 0..23
  const int t = bn >> 3;                    // 0:q 1:k 2:v
  const int nloc0 = (bn & 7) * 128;
  const unsigned short* W = Wqkvb + (size_t)t * 1048576;
  const float* bias = (t == 0) ? bq : (t == 1) ? bk : bv;
  const int tid = threadIdx.x;
  const int lane = tid & 63, w = tid >> 6;
  const int wm = (w >> 1) * 64, wn = (w & 1) * 64;
  const int lanelo = lane & 15, quad = lane >> 4;
  const int row0 = bm * 128;

  f32x4 acc[4][4];
  const f32x4 zf = {0.f, 0.f, 0.f, 0.f};
#pragma unroll
  for (int i = 0; i < 4; ++i)
#pragma unroll
    for (int j = 0; j < 4; ++j) acc[i][j] = zf;

  for (int kt = 0; kt < 16; ++kt) {
#pragma unroll
    for (int p = 0; p < 4; ++p) {
      int c = p * 256 + tid;          // 1024 chunks of 8 bf16 per buffer
      int r = c >> 3, cc = c & 7;
      *(uint4*)(&As[r * 72 + cc * 8]) =
          *(const uint4*)(xb + (size_t)(row0 + r) * 1024 + kt * 64 + cc * 8);
      *(uint4*)(&Bs[r * 72 + cc * 8]) =
          *(const uint4*)(W + (size_t)(nloc0 + r) * 1024 + kt * 64 + cc * 8);
    }
    __syncthreads();
#pragma unroll
    for (int ks = 0; ks < 2; ++ks) {
      bf16x8 a[4], bb[4];
#pragma unroll
      for (int i = 0; i < 4; ++i)
        a[i] = *(const bf16x8*)(&As[(wm + i * 16 + lanelo) * 72 + ks * 32 + quad * 8]);
#pragma unroll
      for (int j = 0; j < 4; ++j)
        bb[j] = *(const bf16x8*)(&Bs[(wn + j * 16 + lanelo) * 72 + ks * 32 + quad * 8]);
#pragma unroll
      for (int i = 0; i < 4; ++i)
#pragma unroll
        for (int j = 0; j < 4; ++j) acc[i][j] = MFMA16(a[i], bb[j], acc[i][j]);
    }
    __syncthreads();
  }
#pragma unroll
  for (int i = 0; i < 4; ++i) {
#pragma unroll
    for (int j = 0; j < 4; ++j) {
      int jj = nloc0 + wn + j * 16 + lanelo;   // 0..1023 within tensor
      int hh = jj >> 7, dc = jj & 127;
      float bvv = bias[jj];
#pragma unroll
      for (int r = 0; r < 4; ++r) {
        int m = row0 + wm + i * 16 + quad * 4 + r;
        int b = m >> 9, s = m & 511;
        float val = acc[i][j][r] + bvv;
        if (mask[b * 512 + s]) val = 0.f;
        unsigned short o = f2bf(val);
        size_t off = ((size_t)(b * 8 + hh) * 512 + s) * 128 + dc;
        if (t == 0) qb[off] = o;
        else if (t == 1) kb[off] = o;
        else {
          vb[off] = o;
          vT[((size_t)(b * 8 + hh) * 128 + dc) * 512 + s] = o;
        }
      }
    }
  }
}

// ---------------------------------------------------------------------------
// K2: rel prep: relb (65x128 bf16 row-major), relT (128x96 bf16, zero-pad).
// ---------------------------------------------------------------------------
__global__ __launch_bounds__(256) void prep_rel(
    const float* __restrict__ rel, unsigned short* __restrict__ relb,
    unsigned short* __restrict__ relT) {
  int i = blockIdx.x * 256 + threadIdx.x;
  if (i < 65 * 128) relb[i] = f2bf(rel[i]);
  if (i < 128 * 96) {
    int d = i / 96, r = i - d * 96;
    relT[i] = (r < 65) ? f2bf(rel[r * 128 + d]) : (unsigned short)0;
  }
}

// ---------------------------------------------------------------------------
// K3: fused bidirectional 2-step RNN. MFMA. LDS rows padded 128->136.
// ---------------------------------------------------------------------------
__global__ __launch_bounds__(256) void rnn_fused(
    const unsigned short* __restrict__ qb, const unsigned short* __restrict__ kb,
    const unsigned short* __restrict__ vb,
    const unsigned short* __restrict__ Wrnnb,
    const float* __restrict__ bihf, const float* __restrict__ bhhf,
    const float* __restrict__ bihb, const float* __restrict__ bhhb,
    unsigned short* __restrict__ rnn_out) {
  __shared__ __align__(16) unsigned short X[65 * 136];   // rows s0-1 .. s0+63
  __shared__ __align__(16) unsigned short Wi[128 * 136];
  __shared__ __align__(16) unsigned short Wh[128 * 136];
  __shared__ __align__(16) unsigned short H1[64 * 136];
  __shared__ float cbf[128], cbb[128];

  const unsigned short* Wihfb = Wrnnb;
  const unsigned short* Whhfb = Wrnnb + 16384;
  const unsigned short* Wihbb = Wrnnb + 32768;
  const unsigned short* Whhbb = Wrnnb + 49152;

  const int gid = blockIdx.x;
  const int tile = gid & 7;
  const int g = gid >> 3;              // 0..95
  const int t = g >> 5;
  const int rem = g & 31;
  const int b = rem >> 2, h = (rem & 3) + 4;
  const int s0 = tile * 64;
  const unsigned short* src = (t == 0) ? qb : (t == 1) ? kb : vb;
  const size_t rowbase = (size_t)(b * 8 + h) * 512;
  const int tid = threadIdx.x;

  for (int c = tid; c < 65 * 16; c += 256) {   // X: 65 rows x 16 chunks
    int r = c >> 4, cc = c & 15;
    uint4 v4;
    if (r == 0 && s0 == 0) v4 = make_uint4(0, 0, 0, 0);
    else v4 = *(const uint4*)(src + (rowbase + (s0 - 1 + r)) * 128 + cc * 8);
    *(uint4*)(&X[r * 136 + cc * 8]) = v4;
  }
#pragma unroll
  for (int p = 0; p < 8; ++p) {       // weights: 2048 chunks of 8 bf16 each
    int c = p * 256 + tid;
    int r = c >> 4, cc = c & 15;
    *(uint4*)(&Wi[r * 136 + cc * 8]) = *(const uint4*)(Wihfb + c * 8);
    *(uint4*)(&Wh[r * 136 + cc * 8]) = *(const uint4*)(Whhfb + c * 8);
  }
  if (tid < 128) {
    cbf[tid] = bihf[tid] + bhhf[tid];
    cbb[tid] = bihb[tid] + bhhb[tid];
  }
  __syncthreads();

  const int lane = tid & 63, w = tid >> 6;
  const int lanelo = lane & 15, quad = lane >> 4;
  const int marow = w * 16 + lanelo;
  const f32x4 zf = {0.f, 0.f, 0.f, 0.f};

  // ---- forward h1 = tanh(Wihf x_{s-1} + cbf) ----
  f32x4 g1[8];
#pragma unroll
  for (int j = 0; j < 8; ++j) g1[j] = zf;
#pragma unroll
  for (int ks = 0; ks < 4; ++ks) {
    bf16x8 a = *(const bf16x8*)(&X[marow * 136 + ks * 32 + quad * 8]);
#pragma unroll
    for (int j = 0; j < 8; ++j) {
      bf16x8 bb = *(const bf16x8*)(&Wi[(j * 16 + lanelo) * 136 + ks * 32 + quad * 8]);
      g1[j] = MFMA16(a, bb, g1[j]);
    }
  }
#pragma unroll
  for (int j = 0; j < 8; ++j) {
    int col = j * 16 + lanelo;
    float cb = cbf[col];
#pragma unroll
    for (int i = 0; i < 4; ++i) {
      int row = w * 16 + quad * 4 + i;
      H1[row * 136 + col] = f2bf(tanhf(g1[j][i] + cb));
    }
  }
  __syncthreads();
  // ---- forward out = tanh(Wihf x_s + Whhf h1 + cbf) ----
  f32x4 a2[8];
#pragma unroll
  for (int j = 0; j < 8; ++j) a2[j] = zf;
#pragma unroll
  for (int ks = 0; ks < 4; ++ks) {
    bf16x8 a = *(const bf16x8*)(&X[(marow + 1) * 136 + ks * 32 + quad * 8]);
#pragma unroll
    for (int j = 0; j < 8; ++j) {
      bf16x8 bb = *(const bf16x8*)(&Wi[(j * 16 + lanelo) * 136 + ks * 32 + quad * 8]);
      a2[j] = MFMA16(a, bb, a2[j]);
    }
  }
#pragma unroll
  for (int ks = 0; ks < 4; ++ks) {
    bf16x8 a = *(const bf16x8*)(&H1[marow * 136 + ks * 32 + quad * 8]);
#pragma unroll
    for (int j = 0; j < 8; ++j) {
      bf16x8 bb = *(const bf16x8*)(&Wh[(j * 16 + lanelo) * 136 + ks * 32 + quad * 8]);
      a2[j] = MFMA16(a, bb, a2[j]);
    }
  }
  float outF[8][4];
#pragma unroll
  for (int j = 0; j < 8; ++j) {
    int col = j * 16 + lanelo;
    float cb = cbf[col];
#pragma unroll
    for (int i = 0; i < 4; ++i) outF[j][i] = tanhf(a2[j][i] + cb);
  }
  __syncthreads();
#pragma unroll
  for (int p = 0; p < 8; ++p) {   // restage backward weights
    int c = p * 256 + tid;
    int r = c >> 4, cc = c & 15;
    *(uint4*)(&Wi[r * 136 + cc * 8]) = *(const uint4*)(Wihbb + c * 8);
    *(uint4*)(&Wh[r * 136 + cc * 8]) = *(const uint4*)(Whhbb + c * 8);
  }
  __syncthreads();
  // ---- backward h1b = tanh(Wihb x_s + cbb) ----
#pragma unroll
  for (int j = 0; j < 8; ++j) g1[j] = zf;
#pragma unroll
  for (int ks = 0; ks < 4; ++ks) {
    bf16x8 a = *(const bf16x8*)(&X[(marow + 1) * 136 + ks * 32 + quad * 8]);
#pragma unroll
    for (int j = 0; j < 8; ++j) {
      bf16x8 bb = *(const bf16x8*)(&Wi[(j * 16 + lanelo) * 136 + ks * 32 + quad * 8]);
      g1[j] = MFMA16(a, bb, g1[j]);
    }
  }
#pragma unroll
  for (int j = 0; j < 8; ++j) {
    int col = j * 16 + lanelo;
    float cb = cbb[col];
#pragma unroll
    for (int i = 0; i < 4; ++i) {
      int row = w * 16 + quad * 4 + i;
      H1[row * 136 + col] = f2bf(tanhf(g1[j][i] + cb));
    }
  }
  __syncthreads();
  // ---- backward out + combine + store ----
#pragma unroll
  for (int j = 0; j < 8; ++j) a2[j] = zf;
#pragma unroll
  for (int ks = 0; ks < 4; ++ks) {
    bf16x8 a = *(const bf16x8*)(&X[marow * 136 + ks * 32 + quad * 8]);
#pragma unroll
    for (int j = 0; j < 8; ++j) {
      bf16x8 bb = *(const bf16x8*)(&Wi[(j * 16 + lanelo) * 136 + ks * 32 + quad * 8]);
      a2[j] = MFMA16(a, bb, a2[j]);
    }
  }
#pragma unroll
  for (int ks = 0; ks < 4; ++ks) {
    bf16x8 a = *(const bf16x8*)(&H1[marow * 136 + ks * 32 + quad * 8]);
#pragma unroll
    for (int j = 0; j < 8; ++j) {
      bf16x8 bb = *(const bf16x8*)(&Wh[(j * 16 + lanelo) * 136 + ks * 32 + quad * 8]);
      a2[j] = MFMA16(a, bb, a2[j]);
    }
  }
#pragma unroll
  for (int j = 0; j < 8; ++j) {
    int col = j * 16 + lanelo;
    float cb = cbb[col];
#pragma unroll
    for (int i = 0; i < 4; ++i) {
      int row = w * 16 + quad * 4 + i;
      float val = outF[j][i] + tanhf(a2[j][i] + cb);
      rnn_out[((size_t)g * 512 + s0 + row) * 128 + col] = f2bf(val);
    }
  }
}

// ---------------------------------------------------------------------------
// K4: copy rnn results back into qb/kb (+vT for v).
// ---------------------------------------------------------------------------
__global__ __launch_bounds__(256) void rnn_copyback(
    const unsigned short* __restrict__ rnn_out,
    unsigned short* __restrict__ qb, unsigned short* __restrict__ kb,
    unsigned short* __restrict__ vT) {
  int idx = blockIdx.x * 256 + threadIdx.x;   // 6,291,456
  int g = idx >> 16;
  int r2 = idx & 65535;
  int s = r2 >> 7, col = r2 & 127;
  int t = g >> 5, rem = g & 31, b = rem >> 2, h = (rem & 3) + 4;
  unsigned short val = rnn_out[idx];
  size_t off = ((size_t)(b * 8 + h) * 512 + s) * 128 + col;
  if (t == 0) qb[off] = val;
  else if (t == 1) kb[off] = val;
  else vT[((size_t)(b * 8 + h) * 128 + col) * 512 + s] = val;
}

// ---------------------------------------------------------------------------
// K5: scores + softmax + buckets. MFMA. As padded 128->136, Bs 32->40.
// ---------------------------------------------------------------------------
__global__ __launch_bounds__(256) void scores_softmax(
    const unsigned short* __restrict__ qbuf, const unsigned short* __restrict__ kbuf,
    const unsigned short* __restrict__ relb, const int* __restrict__ mask,
    float* __restrict__ attn_out, unsigned short* __restrict__ abuf) {
  __shared__ __align__(16) unsigned short As[64 * 136];
  __shared__ __align__(16) unsigned short Bs[512 * 40];
  __shared__ float Ps[64 * 80];
  __shared__ float cmask[512];
  const int idx = blockIdx.x;
  const int qt = idx & 7, bh = idx >> 3, b = bh >> 3;
  const int q0 = qt * 64;
  const size_t qrow0 = (size_t)bh * 512 + q0;
  const int tid = threadIdx.x;

  for (int i = tid; i < 64 * 96; i += 256) abuf[qrow0 * 96 + i] = 0;
  for (int c = tid; c < 1024; c += 256) {
    int r = c >> 4, cc = c & 15;
    *(uint4*)(&As[r * 136 + cc * 8]) = *(const uint4*)(qbuf + (qrow0 + r) * 128 + cc * 8);
  }
  for (int i = tid; i < 512; i += 256) cmask[i] = mask[b * 512 + i] ? -1e9f : 0.f;
  __syncthreads();

  const int lane = tid & 63, w = tid >> 6;
  const int lanelo = lane & 15, quad = lane >> 4;
  const f32x4 zf = {0.f, 0.f, 0.f, 0.f};

  // ---- P: p[q][r] = q . rel[r], r<65 (pad to 80) ----
  f32x4 pacc[5];
#pragma unroll
  for (int j = 0; j < 5; ++j) pacc[j] = zf;
  for (int ks = 0; ks < 4; ++ks) {
    for (int c = tid; c < 320; c += 256) {
      int r = c >> 2, cc = c & 3;
      uint4 v4 = (r < 65) ? *(const uint4*)(relb + r * 128 + ks * 32 + cc * 8)
                          : make_uint4(0, 0, 0, 0);
      *(uint4*)(&Bs[r * 40 + cc * 8]) = v4;
    }
    __syncthreads();
    bf16x8 a = *(const bf16x8*)(&As[(w * 16 + lanelo) * 136 + ks * 32 + quad * 8]);
#pragma unroll
    for (int j = 0; j < 5; ++j) {
      bf16x8 bb = *(const bf16x8*)(&Bs[(j * 16 + lanelo) * 40 + quad * 8]);
      pacc[j] = MFMA16(a, bb, pacc[j]);
    }
    __syncthreads();
  }
#pragma unroll
  for (int j = 0; j < 5; ++j) {
    int col = j * 16 + lanelo;
#pragma unroll
    for (int i = 0; i < 4; ++i) Ps[(w * 16 + quad * 4 + i) * 80 + col] = pacc[j][i];
  }
  __syncthreads();

  // ---- QK: scores tile (64 x 512) ----
  f32x4 acc[32];
#pragma unroll
  for (int j = 0; j < 32; ++j) acc[j] = zf;
  for (int ks = 0; ks < 4; ++ks) {
    for (int c = tid; c < 2048; c += 256) {
      int r = c >> 2, cc = c & 3;
      *(uint4*)(&Bs[r * 40 + cc * 8]) =
          *(const uint4*)(kbuf + ((size_t)bh * 512 + r) * 128 + ks * 32 + cc * 8);
    }
    __syncthreads();
    bf16x8 a = *(const bf16x8*)(&As[(w * 16 + lanelo) * 136 + ks * 32 + quad * 8]);
#pragma unroll
    for (int j = 0; j < 32; ++j) {
      bf16x8 bb = *(const bf16x8*)(&Bs[(j * 16 + lanelo) * 40 + quad * 8]);
      acc[j] = MFMA16(a, bb, acc[j]);
    }
    __syncthreads();
  }

  // ---- softmax ----
  const float rscale = 0.08838834764831845f;  // 1/sqrt(128)
  float mrow[4] = {-1.0e30f, -1.0e30f, -1.0e30f, -1.0e30f};
#pragma unroll
  for (int j = 0; j < 32; ++j) {
    int k = j * 16 + lanelo;
    float cm = cmask[k];
#pragma unroll
    for (int i = 0; i < 4; ++i) {
      int row = w * 16 + quad * 4 + i;
      int qg = q0 + row;
      int d = k - qg;
      int r = min(max(d, -32), 32) + 32;
      float val = (acc[j][i] + Ps[row * 80 + r]) * rscale + cm;
      acc[j][i] = val;
      mrow[i] = fmaxf(mrow[i], val);
    }
  }
#pragma unroll
  for (int st = 1; st < 16; st <<= 1)
#pragma unroll
    for (int i = 0; i < 4; ++i) mrow[i] = fmaxf(mrow[i], __shfl_xor(mrow[i], st, 64));
  float srow[4] = {0.f, 0.f, 0.f, 0.f};
#pragma unroll
  for (int j = 0; j < 32; ++j)
#pragma unroll
    for (int i = 0; i < 4; ++i) {
      float e = __expf(acc[j][i] - mrow[i]);
      acc[j][i] = e;
      srow[i] += e;
    }
#pragma unroll
  for (int st = 1; st < 16; st <<= 1)
#pragma unroll
    for (int i = 0; i < 4; ++i) srow[i] += __shfl_xor(srow[i], st, 64);
  float rs[4];
#pragma unroll
  for (int i = 0; i < 4; ++i) rs[i] = (srow[i] > 0.f) ? 1.f / srow[i] : 0.f;

  // ---- write attn fp32 + buckets ----
  float s0a[4] = {0.f, 0.f, 0.f, 0.f}, s64a[4] = {0.f, 0.f, 0.f, 0.f};
#pragma unroll
  for (int j = 0; j < 32; ++j) {
    int k = j * 16 + lanelo;
#pragma unroll
    for (int i = 0; i < 4; ++i) {
      int row = w * 16 + quad * 4 + i;
      int qg = q0 + row;
      float at = acc[j][i] * rs[i];
      attn_out[((size_t)bh * 512 + qg) * 512 + k] = at;
      int d = k - qg;
      if (d <= -32) s0a[i] += at;
      else if (d >= 32) s64a[i] += at;
      else abuf[((size_t)bh * 512 + qg) * 96 + (d + 32)] = f2bf(at);
    }
  }
#pragma unroll
  for (int st = 1; st < 16; st <<= 1)
#pragma unroll
    for (int i = 0; i < 4; ++i) {
      s0a[i] += __shfl_xor(s0a[i], st, 64);
      s64a[i] += __shfl_xor(s64a[i], st, 64);
    }
  if (lanelo == 0) {
#pragma unroll
    for (int i = 0; i < 4; ++i) {
      int qg = q0 + w * 16 + quad * 4 + i;
      abuf[((size_t)bh * 512 + qg) * 96 + 0] = f2bf(s0a[i]);
      abuf[((size_t)bh * 512 + qg) * 96 + 64] = f2bf(s64a[i]);
    }
  }
}

// ---------------------------------------------------------------------------
// K6: ctx = attn @ v + a @ rel. MFMA. LDS rows padded 32->40.
// ---------------------------------------------------------------------------
__global__ __launch_bounds__(256) void av_ctx(
    const float* __restrict__ attn, const unsigned short* __restrict__ abuf,
    const unsigned short* __restrict__ vT, const unsigned short* __restrict__ relT,
    unsigned short* __restrict__ ctx) {
  __shared__ __align__(16) unsigned short As[64 * 40];
  __shared__ __align__(16) unsigned short Bs[128 * 40];
  const int idx = blockIdx.x;
  const int qt = idx & 7, bh = idx >> 3;
  const int q0 = qt * 64;
  const int tid = threadIdx.x, lane = tid & 63, w = tid >> 6;
  const int lanelo = lane & 15, quad = lane >> 4;
  const f32x4 zf = {0.f, 0.f, 0.f, 0.f};
  f32x4 acc[8];
#pragma unroll
  for (int j = 0; j < 8; ++j) acc[j] = zf;

  for (int kt = 0; kt < 19; ++kt) {
    {  // stage A (64x32): 256 chunks of 8
      int c = tid;
      int r = c >> 2, cc = c & 3;
      if (kt < 16) {
        const float* src = attn + ((size_t)bh * 512 + q0 + r) * 512 + kt * 32 + cc * 8;
        *(uint2*)(&As[r * 40 + cc * 8]) = pack4(*(const float4*)(src));
        *(uint2*)(&As[r * 40 + cc * 8 + 4]) = pack4(*(const float4*)(src + 4));
      } else {
        *(uint4*)(&As[r * 40 + cc * 8]) =
            *(const uint4*)(abuf + ((size_t)bh * 512 + q0 + r) * 96 + (kt - 16) * 32 + cc * 8);
      }
    }
#pragma unroll
    for (int p = 0; p < 2; ++p) {  // stage B (128x32): 512 chunks of 8
      int c = p * 256 + tid;
      int r = c >> 2, cc = c & 3;
      uint4 vbv;
      if (kt < 16)
        vbv = *(const uint4*)(vT + ((size_t)bh * 128 + r) * 512 + kt * 32 + cc * 8);
      else
        vbv = *(const uint4*)(relT + r * 96 + (kt - 16) * 32 + cc * 8);
      *(uint4*)(&Bs[r * 40 + cc * 8]) = vbv;
    }
    __syncthreads();
    bf16x8 a = *(const bf16x8*)(&As[(w * 16 + lanelo) * 40 + quad * 8]);
#pragma unroll
    for (int j = 0; j < 8; ++j) {
      bf16x8 bb = *(const bf16x8*)(&Bs[(j * 16 + lanelo) * 40 + quad * 8]);
      acc[j] = MFMA16(a, bb, acc[j]);
    }
    __syncthreads();
  }
  const int b = bh >> 3, h = bh & 7;
#pragma unroll
  for (int j = 0; j < 8; ++j) {
    int d = j * 16 + lanelo;
#pragma unroll
    for (int i = 0; i < 4; ++i) {
      int qg = q0 + w * 16 + quad * 4 + i;
      ctx[((size_t)(b * 512 + qg)) * 1024 + h * 128 + d] = f2bf(acc[j][i]);
    }
  }
}

// ---------------------------------------------------------------------------
// K7: out = ctx @ Wo^T + bo. MFMA 128x128 tiles; LDS rows padded 64->72.
// ---------------------------------------------------------------------------
__global__ __launch_bounds__(256) void out_proj(
    const unsigned short* __restrict__ ctx, const unsigned short* __restrict__ Wob,
    const float* __restrict__ bo, float* __restrict__ outp) {
  __shared__ __align__(16) unsigned short As[128 * 72];
  __shared__ __align__(16) unsigned short Bs[128 * 72];
  const int bm = blockIdx.x & 31, bn = blockIdx.x >> 5;
  const int tid = threadIdx.x, lane = tid & 63, w = tid >> 6;
  const int wm = (w >> 1) * 64, wn = (w & 1) * 64;
  const int lanelo = lane & 15, quad = lane >> 4;
  const int row0 = bm * 128, col0 = bn * 128;
  f32x4 acc[4][4];
  const f32x4 zf = {0.f, 0.f, 0.f, 0.f};
#pragma unroll
  for (int i = 0; i < 4; ++i)
#pragma unroll
    for (int j = 0; j < 4; ++j) acc[i][j] = zf;

  for (int kt = 0; kt < 16; ++kt) {
#pragma unroll
    for (int p = 0; p < 4; ++p) {
      int c = p * 256 + tid;
      int r = c >> 3, cc = c & 7;
      *(uint4*)(&As[r * 72 + cc * 8]) =
          *(const uint4*)(ctx + (size_t)(row0 + r) * 1024 + kt * 64 + cc * 8);
      *(uint4*)(&Bs[r * 72 + cc * 8]) =
          *(const uint4*)(Wob + (size_t)(col0 + r) * 1024 + kt * 64 + cc * 8);
    }
    __syncthreads();
#pragma unroll
    for (int ks = 0; ks < 2; ++ks) {
      bf16x8 a[4], bb[4];
#pragma unroll
      for (int i = 0; i < 4; ++i)
        a[i] = *(const bf16x8*)(&As[(wm + i * 16 + lanelo) * 72 + ks * 32 + quad * 8]);
#pragma unroll
      for (int j = 0; j < 4; ++j)
        bb[j] = *(const bf16x8*)(&Bs[(wn + j * 16 + lanelo) * 72 + ks * 32 + quad * 8]);
#pragma unroll
      for (int i = 0; i < 4; ++i)
#pragma unroll
        for (int j = 0; j < 4; ++j) acc[i][j] = MFMA16(a[i], bb[j], acc[i][j]);
    }
    __syncthreads();
  }
#pragma unroll
  for (int i = 0; i < 4; ++i) {
#pragma unroll
    for (int j = 0; j < 4; ++j) {
      int n = col0 + wn + j * 16 + lanelo;
      float bbv = bo[n];
#pragma unroll
      for (int r = 0; r < 4; ++r) {
        int m = row0 + wm + i * 16 + quad * 4 + r;
        outp[(size_t)m * 1024 + n] = acc[i][j][r] + bbv;
      }
    }
  }
}

// ---------------------------------------------------------------------------
extern "C" void kernel_launch(void* const* d_in, const int* in_sizes, int n_in,
                              void* d_out, int out_size, void* d_ws, size_t ws_size,
                              hipStream_t stream) {
  const float* x    = (const float*)d_in[0];
  const int*   mask = (const int*)d_in[1];
  const float* Wq   = (const float*)d_in[2];
  const float* bq   = (const float*)d_in[3];
  const float* Wk   = (const float*)d_in[4];
  const float* bk   = (const float*)d_in[5];
  const float* Wv   = (const float*)d_in[6];
  const float* bv   = (const float*)d_in[7];
  const float* Wo   = (const float*)d_in[8];
  const float* bo   = (const float*)d_in[9];
  const float* rel  = (const float*)d_in[10];
  const float* Wihf = (const float*)d_in[11];
  const float* Whhf = (const float*)d_in[12];
  const float* bihf = (const float*)d_in[13];
  const float* bhhf = (const float*)d_in[14];
  const float* Wihb = (const float*)d_in[15];
  const float* Whhb = (const float*)d_in[16];
  const float* bihb = (const float*)d_in[17];
  const float* bhhb = (const float*)d_in[18];

  // ws: 33,595,904 bytes used (proven-safe <= 33,702,144)
  char* ws = (char*)d_ws;
  unsigned short* qb   = (unsigned short*)(ws + 0);          // 8,388,608 B
  unsigned short* kb   = (unsigned short*)(ws + 8388608);    // 8,388,608 B
  unsigned short* vT   = (unsigned short*)(ws + 16777216);   // 8,388,608 B
  unsigned short* abuf = (unsigned short*)(ws + 25165824);   // 6,291,456 B (32768x96)
  unsigned short* relb = (unsigned short*)(ws + 31457280);   //    16,640 B
  unsigned short* relT = (unsigned short*)(ws + 31473920);   //    24,576 B
  unsigned short* Wob  = (unsigned short*)(ws + 31498496);   // 2,097,152 B
  unsigned short* ctx  = qb;   // qb dead after scores_softmax

  float* outp  = (float*)d_out;
  float* attnF = outp + 4194304;                 // (B,H,S,S) fp32 = 67.1 MB
  // bf16 scratch inside the attn region; all dead before scores_softmax
  // overwrites the whole region with fp32 attn:
  unsigned short* abase  = (unsigned short*)attnF;
  unsigned short* xb     = abase;                 // 4,194,304 elems
  unsigned short* vb     = abase + 4194304;       // 4,194,304 elems
  unsigned short* rnnout = abase + 8388608;       // 6,291,456 elems
  unsigned short* Wqkvb  = abase + 14680064;      // 3,145,728 elems
  unsigned short* Wrnnb  = abase + 17825792;      //    65,536 elems

  prep_bf16<<<dim3(8256), dim3(256), 0, stream>>>(
      x, Wq, Wk, Wv, Wo, Wihf, Whhf, Wihb, Whhb, xb, Wqkvb, Wob, Wrnnb);
  prep_rel<<<dim3(48), dim3(256), 0, stream>>>(rel, relb, relT);
  qkv_proj<<<dim3(768), dim3(256), 0, stream>>>(xb, Wqkvb, bq, bk, bv, mask,
                                                qb, kb, vb, vT);
  rnn_fused<<<dim3(768), dim3(256), 0, stream>>>(qb, kb, vb, Wrnnb,
                                                 bihf, bhhf, bihb, bhhb, rnnout);
  rnn_copyback<<<dim3(24576), dim3(256), 0, stream>>>(rnnout, qb, kb, vT);
  scores_softmax<<<dim3(512), dim3(256), 0, stream>>>(qb, kb, relb, mask, attnF, abuf);
  av_ctx<<<dim3(512), dim3(256), 0, stream>>>(attnF, abuf, vT, relT, ctx);
  out_proj<<<dim3(256), dim3(256), 0, stream>>>(ctx, Wob, bo, outp);
}

// Round 9
// 355.480 us; speedup vs baseline: 12.2745x; 1.0504x over previous
//
#include <hip/hip_runtime.h>

// ---------------------------------------------------------------------------
// MultiHeadedAttention w/ n-gram RNN heads + rel-pos embeddings. MFMA version.
// B=8 S=512 D=1024 H=8 DPH=128, MAX_REL=32, NG heads 4..7.
// I/O: float tensors FP32 (verified R5); mask int32. Internals bf16+MFMA.
// R9: global_load_lds(16B) DMA staging with source-side rotate swizzle
// (unpadded LDS tiles; lane fetches chunk (p - row) & mod so fragment reads
// keep R8's conflict-free-ish bank pattern). Applied to qkv_proj, out_proj,
// scores Bs, av_ctx Bs. Packed vT epilogue stores.
//
// ws (33,595,904 B): qb | kb | vT | abuf | relb | relT | Wob.  ctx aliases qb.
// d_out attn-region scratch (dead before scores overwrites with fp32 attn):
//   xb | vb | rnnout | Wqkvb | Wrnnb.
// ---------------------------------------------------------------------------

typedef __bf16 bf16x8 __attribute__((ext_vector_type(8)));
typedef float f32x4 __attribute__((ext_vector_type(4)));

#define MFMA16(a, b, c) __builtin_amdgcn_mfma_f32_16x16x32_bf16(a, b, c, 0, 0, 0)

__device__ __forceinline__ unsigned short f2bf(float f) {
  unsigned u = __float_as_uint(f);
  u += 0x7FFFu + ((u >> 16) & 1u);
  return (unsigned short)(u >> 16);
}
__device__ __forceinline__ uint2 pack4(float4 f) {
  uint2 r;
  r.x = (unsigned)f2bf(f.x) | ((unsigned)f2bf(f.y) << 16);
  r.y = (unsigned)f2bf(f.z) | ((unsigned)f2bf(f.w) << 16);
  return r;
}
// async 16B global->LDS DMA; dest = wave-uniform lds base + lane*16
__device__ __forceinline__ void gld16(const unsigned short* g, unsigned short* l) {
  __builtin_amdgcn_global_load_lds(
      (const __attribute__((address_space(1))) unsigned int*)g,
      (__attribute__((address_space(3))) unsigned int*)l, 16, 0, 0);
}

// ---------------------------------------------------------------------------
// K0: one-shot fp32->bf16 conversion of x, Wq|Wk|Wv, Wo, RNN weights.
// ---------------------------------------------------------------------------
__global__ __launch_bounds__(256) void prep_bf16(
    const float* __restrict__ x,
    const float* __restrict__ Wq, const float* __restrict__ Wk,
    const float* __restrict__ Wv, const float* __restrict__ Wo,
    const float* __restrict__ Wihf, const float* __restrict__ Whhf,
    const float* __restrict__ Wihb, const float* __restrict__ Whhb,
    unsigned short* __restrict__ xb, unsigned short* __restrict__ Wqkvb,
    unsigned short* __restrict__ Wob, unsigned short* __restrict__ Wrnnb) {
  int i = blockIdx.x * 256 + threadIdx.x;   // float4 index
  const float* src;
  unsigned short* dst;
  int off;
  if (i < 1048576) {                    // x
    src = x; dst = xb; off = i;
  } else if (i < 1310720) {             // Wq
    src = Wq; dst = Wqkvb; off = i - 1048576;
  } else if (i < 1572864) {             // Wk
    src = Wk; dst = Wqkvb + 1048576; off = i - 1310720;
  } else if (i < 1835008) {             // Wv
    src = Wv; dst = Wqkvb + 2097152; off = i - 1572864;
  } else if (i < 2097152) {             // Wo
    src = Wo; dst = Wob; off = i - 1835008;
  } else if (i < 2101248) {             // Wihf
    src = Wihf; dst = Wrnnb; off = i - 2097152;
  } else if (i < 2105344) {             // Whhf
    src = Whhf; dst = Wrnnb + 16384; off = i - 2101248;
  } else if (i < 2109440) {             // Wihb
    src = Wihb; dst = Wrnnb + 32768; off = i - 2105344;
  } else {                              // Whhb
    src = Whhb; dst = Wrnnb + 49152; off = i - 2109440;
  }
  float4 f = *((const float4*)src + off);
  *(uint2*)(dst + (size_t)off * 4) = pack4(f);
}

// ---------------------------------------------------------------------------
// K1: QKV projection. 128x128 tiles, MFMA, DMA staging w/ rot8 swizzle.
// ---------------------------------------------------------------------------
__global__ __launch_bounds__(256) void qkv_proj(
    const unsigned short* __restrict__ xb, const unsigned short* __restrict__ Wqkvb,
    const float* __restrict__ bq, const float* __restrict__ bk,
    const float* __restrict__ bv, const int* __restrict__ mask,
    unsigned short* __restrict__ qb, unsigned short* __restrict__ kb,
    unsigned short* __restrict__ vb, unsigned short* __restrict__ vT) {
  __shared__ __align__(16) unsigned short As[128 * 64];
  __shared__ __align__(16) unsigned short Bs[128 * 64];
  const int bm = blockIdx.x & 31;
  const int bn = blockIdx.x >> 5;           // 0..23
  const int t = bn >> 3;                    // 0:q 1:k 2:v
  const int nloc0 = (bn & 7) * 128;
  const unsigned short* W = Wqkvb + (size_t)t * 1048576;
  const float* bias = (t == 0) ? bq : (t == 1) ? bk : bv;
  const int tid = threadIdx.x;
  const int lane = tid & 63, w = tid >> 6;
  const int wm = (w >> 1) * 64, wn = (w & 1) * 64;
  const int lanelo = lane & 15, quad = lane >> 4;
  const int row0 = bm * 128;
  const int rloc = lane >> 3, pch = lane & 7;
  const int lch = (pch - rloc) & 7;         // source chunk for rot8 swizzle

  f32x4 acc[4][4];
  const f32x4 zf = {0.f, 0.f, 0.f, 0.f};
#pragma unroll
  for (int i = 0; i < 4; ++i)
#pragma unroll
    for (int j = 0; j < 4; ++j) acc[i][j] = zf;

  for (int kt = 0; kt < 16; ++kt) {
#pragma unroll
    for (int q = 0; q < 4; ++q) {        // 16 segments of 8 rows; 4 per wave
      int seg = w * 4 + q;
      int grow = seg * 8 + rloc;
      gld16(xb + (size_t)(row0 + grow) * 1024 + kt * 64 + lch * 8, &As[seg * 512]);
      gld16(W + (size_t)(nloc0 + grow) * 1024 + kt * 64 + lch * 8, &Bs[seg * 512]);
    }
    __syncthreads();
#pragma unroll
    for (int ks = 0; ks < 2; ++ks) {
      const int pA = (ks * 4 + quad + lanelo) & 7;   // rotated phys chunk
      bf16x8 a[4], bb[4];
#pragma unroll
      for (int i = 0; i < 4; ++i)
        a[i] = *(const bf16x8*)(&As[(wm + i * 16 + lanelo) * 64 + pA * 8]);
#pragma unroll
      for (int j = 0; j < 4; ++j)
        bb[j] = *(const bf16x8*)(&Bs[(wn + j * 16 + lanelo) * 64 + pA * 8]);
#pragma unroll
      for (int i = 0; i < 4; ++i)
#pragma unroll
        for (int j = 0; j < 4; ++j) acc[i][j] = MFMA16(a[i], bb[j], acc[i][j]);
    }
    __syncthreads();
  }
#pragma unroll
  for (int i = 0; i < 4; ++i) {
#pragma unroll
    for (int j = 0; j < 4; ++j) {
      int jj = nloc0 + wn + j * 16 + lanelo;   // 0..1023 within tensor
      int hh = jj >> 7, dc = jj & 127;
      float bvv = bias[jj];
      int m0 = row0 + wm + i * 16 + quad * 4;
      int b0 = m0 >> 9, sS = m0 & 511;
      unsigned short ov[4];
#pragma unroll
      for (int r = 0; r < 4; ++r) {
        int s = sS + r;
        float val = acc[i][j][r] + bvv;
        if (mask[b0 * 512 + s]) val = 0.f;
        unsigned short o = f2bf(val);
        ov[r] = o;
        size_t off = ((size_t)(b0 * 8 + hh) * 512 + s) * 128 + dc;
        if (t == 0) qb[off] = o;
        else if (t == 1) kb[off] = o;
        else vb[off] = o;
      }
      if (t == 2) {
        uint2 pk;
        pk.x = (unsigned)ov[0] | ((unsigned)ov[1] << 16);
        pk.y = (unsigned)ov[2] | ((unsigned)ov[3] << 16);
        *(uint2*)(&vT[((size_t)(b0 * 8 + hh) * 128 + dc) * 512 + sS]) = pk;
      }
    }
  }
}

// ---------------------------------------------------------------------------
// K2: rel prep: relb (65x128 bf16 row-major), relT (128x96 bf16, zero-pad).
// ---------------------------------------------------------------------------
__global__ __launch_bounds__(256) void prep_rel(
    const float* __restrict__ rel, unsigned short* __restrict__ relb,
    unsigned short* __restrict__ relT) {
  int i = blockIdx.x * 256 + threadIdx.x;
  if (i < 65 * 128) relb[i] = f2bf(rel[i]);
  if (i < 128 * 96) {
    int d = i / 96, r = i - d * 96;
    relT[i] = (r < 65) ? f2bf(rel[r * 128 + d]) : (unsigned short)0;
  }
}

// ---------------------------------------------------------------------------
// K3: fused bidirectional 2-step RNN. MFMA. LDS rows padded 128->136 (R8).
// ---------------------------------------------------------------------------
__global__ __launch_bounds__(256) void rnn_fused(
    const unsigned short* __restrict__ qb, const unsigned short* __restrict__ kb,
    const unsigned short* __restrict__ vb,
    const unsigned short* __restrict__ Wrnnb,
    const float* __restrict__ bihf, const float* __restrict__ bhhf,
    const float* __restrict__ bihb, const float* __restrict__ bhhb,
    unsigned short* __restrict__ rnn_out) {
  __shared__ __align__(16) unsigned short X[65 * 136];   // rows s0-1 .. s0+63
  __shared__ __align__(16) unsigned short Wi[128 * 136];
  __shared__ __align__(16) unsigned short Wh[128 * 136];
  __shared__ __align__(16) unsigned short H1[64 * 136];
  __shared__ float cbf[128], cbb[128];

  const unsigned short* Wihfb = Wrnnb;
  const unsigned short* Whhfb = Wrnnb + 16384;
  const unsigned short* Wihbb = Wrnnb + 32768;
  const unsigned short* Whhbb = Wrnnb + 49152;

  const int gid = blockIdx.x;
  const int tile = gid & 7;
  const int g = gid >> 3;              // 0..95
  const int t = g >> 5;
  const int rem = g & 31;
  const int b = rem >> 2, h = (rem & 3) + 4;
  const int s0 = tile * 64;
  const unsigned short* src = (t == 0) ? qb : (t == 1) ? kb : vb;
  const size_t rowbase = (size_t)(b * 8 + h) * 512;
  const int tid = threadIdx.x;

  for (int c = tid; c < 65 * 16; c += 256) {   // X: 65 rows x 16 chunks
    int r = c >> 4, cc = c & 15;
    uint4 v4;
    if (r == 0 && s0 == 0) v4 = make_uint4(0, 0, 0, 0);
    else v4 = *(const uint4*)(src + (rowbase + (s0 - 1 + r)) * 128 + cc * 8);
    *(uint4*)(&X[r * 136 + cc * 8]) = v4;
  }
#pragma unroll
  for (int p = 0; p < 8; ++p) {       // weights: 2048 chunks of 8 bf16 each
    int c = p * 256 + tid;
    int r = c >> 4, cc = c & 15;
    *(uint4*)(&Wi[r * 136 + cc * 8]) = *(const uint4*)(Wihfb + c * 8);
    *(uint4*)(&Wh[r * 136 + cc * 8]) = *(const uint4*)(Whhfb + c * 8);
  }
  if (tid < 128) {
    cbf[tid] = bihf[tid] + bhhf[tid];
    cbb[tid] = bihb[tid] + bhhb[tid];
  }
  __syncthreads();

  const int lane = tid & 63, w = tid >> 6;
  const int lanelo = lane & 15, quad = lane >> 4;
  const int marow = w * 16 + lanelo;
  const f32x4 zf = {0.f, 0.f, 0.f, 0.f};

  // ---- forward h1 = tanh(Wihf x_{s-1} + cbf) ----
  f32x4 g1[8];
#pragma unroll
  for (int j = 0; j < 8; ++j) g1[j] = zf;
#pragma unroll
  for (int ks = 0; ks < 4; ++ks) {
    bf16x8 a = *(const bf16x8*)(&X[marow * 136 + ks * 32 + quad * 8]);
#pragma unroll
    for (int j = 0; j < 8; ++j) {
      bf16x8 bb = *(const bf16x8*)(&Wi[(j * 16 + lanelo) * 136 + ks * 32 + quad * 8]);
      g1[j] = MFMA16(a, bb, g1[j]);
    }
  }
#pragma unroll
  for (int j = 0; j < 8; ++j) {
    int col = j * 16 + lanelo;
    float cb = cbf[col];
#pragma unroll
    for (int i = 0; i < 4; ++i) {
      int row = w * 16 + quad * 4 + i;
      H1[row * 136 + col] = f2bf(tanhf(g1[j][i] + cb));
    }
  }
  __syncthreads();
  // ---- forward out = tanh(Wihf x_s + Whhf h1 + cbf) ----
  f32x4 a2[8];
#pragma unroll
  for (int j = 0; j < 8; ++j) a2[j] = zf;
#pragma unroll
  for (int ks = 0; ks < 4; ++ks) {
    bf16x8 a = *(const bf16x8*)(&X[(marow + 1) * 136 + ks * 32 + quad * 8]);
#pragma unroll
    for (int j = 0; j < 8; ++j) {
      bf16x8 bb = *(const bf16x8*)(&Wi[(j * 16 + lanelo) * 136 + ks * 32 + quad * 8]);
      a2[j] = MFMA16(a, bb, a2[j]);
    }
  }
#pragma unroll
  for (int ks = 0; ks < 4; ++ks) {
    bf16x8 a = *(const bf16x8*)(&H1[marow * 136 + ks * 32 + quad * 8]);
#pragma unroll
    for (int j = 0; j < 8; ++j) {
      bf16x8 bb = *(const bf16x8*)(&Wh[(j * 16 + lanelo) * 136 + ks * 32 + quad * 8]);
      a2[j] = MFMA16(a, bb, a2[j]);
    }
  }
  float outF[8][4];
#pragma unroll
  for (int j = 0; j < 8; ++j) {
    int col = j * 16 + lanelo;
    float cb = cbf[col];
#pragma unroll
    for (int i = 0; i < 4; ++i) outF[j][i] = tanhf(a2[j][i] + cb);
  }
  __syncthreads();
#pragma unroll
  for (int p = 0; p < 8; ++p) {   // restage backward weights
    int c = p * 256 + tid;
    int r = c >> 4, cc = c & 15;
    *(uint4*)(&Wi[r * 136 + cc * 8]) = *(const uint4*)(Wihbb + c * 8);
    *(uint4*)(&Wh[r * 136 + cc * 8]) = *(const uint4*)(Whhbb + c * 8);
  }
  __syncthreads();
  // ---- backward h1b = tanh(Wihb x_s + cbb) ----
#pragma unroll
  for (int j = 0; j < 8; ++j) g1[j] = zf;
#pragma unroll
  for (int ks = 0; ks < 4; ++ks) {
    bf16x8 a = *(const bf16x8*)(&X[(marow + 1) * 136 + ks * 32 + quad * 8]);
#pragma unroll
    for (int j = 0; j < 8; ++j) {
      bf16x8 bb = *(const bf16x8*)(&Wi[(j * 16 + lanelo) * 136 + ks * 32 + quad * 8]);
      g1[j] = MFMA16(a, bb, g1[j]);
    }
  }
#pragma unroll
  for (int j = 0; j < 8; ++j) {
    int col = j * 16 + lanelo;
    float cb = cbb[col];
#pragma unroll
    for (int i = 0; i < 4; ++i) {
      int row = w * 16 + quad * 4 + i;
      H1[row * 136 + col] = f2bf(tanhf(g1[j][i] + cb));
    }
  }
  __syncthreads();
  // ---- backward out + combine + store ----
#pragma unroll
  for (int j = 0; j < 8; ++j) a2[j] = zf;
#pragma unroll
  for (int ks = 0; ks < 4; ++ks) {
    bf16x8 a = *(const bf16x8*)(&X[marow * 136 + ks * 32 + quad * 8]);
#pragma unroll
    for (int j = 0; j < 8; ++j) {
      bf16x8 bb = *(const bf16x8*)(&Wi[(j * 16 + lanelo) * 136 + ks * 32 + quad * 8]);
      a2[j] = MFMA16(a, bb, a2[j]);
    }
  }
#pragma unroll
  for (int ks = 0; ks < 4; ++ks) {
    bf16x8 a = *(const bf16x8*)(&H1[marow * 136 + ks * 32 + quad * 8]);
#pragma unroll
    for (int j = 0; j < 8; ++j) {
      bf16x8 bb = *(const bf16x8*)(&Wh[(j * 16 + lanelo) * 136 + ks * 32 + quad * 8]);
      a2[j] = MFMA16(a, bb, a2[j]);
    }
  }
#pragma unroll
  for (int j = 0; j < 8; ++j) {
    int col = j * 16 + lanelo;
    float cb = cbb[col];
#pragma unroll
    for (int i = 0; i < 4; ++i) {
      int row = w * 16 + quad * 4 + i;
      float val = outF[j][i] + tanhf(a2[j][i] + cb);
      rnn_out[((size_t)g * 512 + s0 + row) * 128 + col] = f2bf(val);
    }
  }
}

// ---------------------------------------------------------------------------
// K4: copy rnn results back into qb/kb (+vT for v).
// ---------------------------------------------------------------------------
__global__ __launch_bounds__(256) void rnn_copyback(
    const unsigned short* __restrict__ rnn_out,
    unsigned short* __restrict__ qb, unsigned short* __restrict__ kb,
    unsigned short* __restrict__ vT) {
  int idx = blockIdx.x * 256 + threadIdx.x;   // 6,291,456
  int g = idx >> 16;
  int r2 = idx & 65535;
  int s = r2 >> 7, col = r2 & 127;
  int t = g >> 5, rem = g & 31, b = rem >> 2, h = (rem & 3) + 4;
  unsigned short val = rnn_out[idx];
  size_t off = ((size_t)(b * 8 + h) * 512 + s) * 128 + col;
  if (t == 0) qb[off] = val;
  else if (t == 1) kb[off] = val;
  else vT[((size_t)(b * 8 + h) * 128 + col) * 512 + s] = val;
}

// ---------------------------------------------------------------------------
// K5: scores + softmax + buckets. MFMA. As padded 136 (manual, once);
// Bs unpadded 512x32 w/ rot4 swizzle + DMA staging. LDS 72.7 KB -> 2 blk/CU.
// ---------------------------------------------------------------------------
__global__ __launch_bounds__(256) void scores_softmax(
    const unsigned short* __restrict__ qbuf, const unsigned short* __restrict__ kbuf,
    const unsigned short* __restrict__ relb, const int* __restrict__ mask,
    float* __restrict__ attn_out, unsigned short* __restrict__ abuf) {
  __shared__ __align__(16) unsigned short As[64 * 136];
  __shared__ __align__(16) unsigned short Bs[512 * 32];
  __shared__ float Ps[64 * 80];
  __shared__ float cmask[512];
  const int idx = blockIdx.x;
  const int qt = idx & 7, bh = idx >> 3, b = bh >> 3;
  const int q0 = qt * 64;
  const size_t qrow0 = (size_t)bh * 512 + q0;
  const int tid = threadIdx.x;

  for (int i = tid; i < 64 * 96; i += 256) abuf[qrow0 * 96 + i] = 0;
  for (int c = tid; c < 1024; c += 256) {
    int r = c >> 4, cc = c & 15;
    *(uint4*)(&As[r * 136 + cc * 8]) = *(const uint4*)(qbuf + (qrow0 + r) * 128 + cc * 8);
  }
  for (int i = tid; i < 512; i += 256) cmask[i] = mask[b * 512 + i] ? -1e9f : 0.f;
  __syncthreads();

  const int lane = tid & 63, w = tid >> 6;
  const int lanelo = lane & 15, quad = lane >> 4;
  const int rloc4 = lane >> 2, pch4 = lane & 3;
  const int lch4 = (pch4 - rloc4) & 3;        // rot4 source chunk
  const int pB = (quad + lanelo) & 3;         // rotated phys chunk for reads
  const f32x4 zf = {0.f, 0.f, 0.f, 0.f};

  // ---- P: p[q][r] = q . rel[r], r<65 (cols 65..79 garbage, never read) ----
  f32x4 pacc[5];
#pragma unroll
  for (int j = 0; j < 5; ++j) pacc[j] = zf;
  for (int ks = 0; ks < 4; ++ks) {
    for (int c = tid; c < 320; c += 256) {
      int r = c >> 2, cc = c & 3;
      uint4 v4 = (r < 65) ? *(const uint4*)(relb + r * 128 + ks * 32 + cc * 8)
                          : make_uint4(0, 0, 0, 0);
      *(uint4*)(&Bs[r * 32 + ((cc + r) & 3) * 8]) = v4;   // rot4 layout
    }
    __syncthreads();
    bf16x8 a = *(const bf16x8*)(&As[(w * 16 + lanelo) * 136 + ks * 32 + quad * 8]);
#pragma unroll
    for (int j = 0; j < 5; ++j) {
      bf16x8 bb = *(const bf16x8*)(&Bs[(j * 16 + lanelo) * 32 + pB * 8]);
      pacc[j] = MFMA16(a, bb, pacc[j]);
    }
    __syncthreads();
  }
#pragma unroll
  for (int j = 0; j < 5; ++j) {
    int col = j * 16 + lanelo;
#pragma unroll
    for (int i = 0; i < 4; ++i) Ps[(w * 16 + quad * 4 + i) * 80 + col] = pacc[j][i];
  }
  __syncthreads();

  // ---- QK: scores tile (64 x 512), DMA-staged K ----
  f32x4 acc[32];
#pragma unroll
  for (int j = 0; j < 32; ++j) acc[j] = zf;
  for (int ks = 0; ks < 4; ++ks) {
#pragma unroll
    for (int q = 0; q < 8; ++q) {     // 32 segments of 16 rows; 8 per wave
      int seg = w * 8 + q;
      int grow = seg * 16 + rloc4;    // 0..511
      gld16(kbuf + ((size_t)bh * 512 + grow) * 128 + ks * 32 + lch4 * 8,
            &Bs[seg * 512]);
    }
    __syncthreads();
    bf16x8 a = *(const bf16x8*)(&As[(w * 16 + lanelo) * 136 + ks * 32 + quad * 8]);
#pragma unroll
    for (int j = 0; j < 32; ++j) {
      bf16x8 bb = *(const bf16x8*)(&Bs[(j * 16 + lanelo) * 32 + pB * 8]);
      acc[j] = MFMA16(a, bb, acc[j]);
    }
    __syncthreads();
  }

  // ---- softmax ----
  const float rscale = 0.08838834764831845f;  // 1/sqrt(128)
  float mrow[4] = {-1.0e30f, -1.0e30f, -1.0e30f, -1.0e30f};
#pragma unroll
  for (int j = 0; j < 32; ++j) {
    int k = j * 16 + lanelo;
    float cm = cmask[k];
#pragma unroll
    for (int i = 0; i < 4; ++i) {
      int row = w * 16 + quad * 4 + i;
      int qg = q0 + row;
      int d = k - qg;
      int r = min(max(d, -32), 32) + 32;
      float val = (acc[j][i] + Ps[row * 80 + r]) * rscale + cm;
      acc[j][i] = val;
      mrow[i] = fmaxf(mrow[i], val);
    }
  }
#pragma unroll
  for (int st = 1; st < 16; st <<= 1)
#pragma unroll
    for (int i = 0; i < 4; ++i) mrow[i] = fmaxf(mrow[i], __shfl_xor(mrow[i], st, 64));
  float srow[4] = {0.f, 0.f, 0.f, 0.f};
#pragma unroll
  for (int j = 0; j < 32; ++j)
#pragma unroll
    for (int i = 0; i < 4; ++i) {
      float e = __expf(acc[j][i] - mrow[i]);
      acc[j][i] = e;
      srow[i] += e;
    }
#pragma unroll
  for (int st = 1; st < 16; st <<= 1)
#pragma unroll
    for (int i = 0; i < 4; ++i) srow[i] += __shfl_xor(srow[i], st, 64);
  float rs[4];
#pragma unroll
  for (int i = 0; i < 4; ++i) rs[i] = (srow[i] > 0.f) ? 1.f / srow[i] : 0.f;

  // ---- write attn fp32 + buckets ----
  float s0a[4] = {0.f, 0.f, 0.f, 0.f}, s64a[4] = {0.f, 0.f, 0.f, 0.f};
#pragma unroll
  for (int j = 0; j < 32; ++j) {
    int k = j * 16 + lanelo;
#pragma unroll
    for (int i = 0; i < 4; ++i) {
      int row = w * 16 + quad * 4 + i;
      int qg = q0 + row;
      float at = acc[j][i] * rs[i];
      attn_out[((size_t)bh * 512 + qg) * 512 + k] = at;
      int d = k - qg;
      if (d <= -32) s0a[i] += at;
      else if (d >= 32) s64a[i] += at;
      else abuf[((size_t)bh * 512 + qg) * 96 + (d + 32)] = f2bf(at);
    }
  }
#pragma unroll
  for (int st = 1; st < 16; st <<= 1)
#pragma unroll
    for (int i = 0; i < 4; ++i) {
      s0a[i] += __shfl_xor(s0a[i], st, 64);
      s64a[i] += __shfl_xor(s64a[i], st, 64);
    }
  if (lanelo == 0) {
#pragma unroll
    for (int i = 0; i < 4; ++i) {
      int qg = q0 + w * 16 + quad * 4 + i;
      abuf[((size_t)bh * 512 + qg) * 96 + 0] = f2bf(s0a[i]);
      abuf[((size_t)bh * 512 + qg) * 96 + 64] = f2bf(s64a[i]);
    }
  }
}

// ---------------------------------------------------------------------------
// K6: ctx = attn @ v + a @ rel. MFMA. As padded 40 (manual, fp32 pack);
// Bs unpadded 128x32 w/ rot4 + DMA.
// ---------------------------------------------------------------------------
__global__ __launch_bounds__(256) void av_ctx(
    const float* __restrict__ attn, const unsigned short* __restrict__ abuf,
    const unsigned short* __restrict__ vT, const unsigned short* __restrict__ relT,
    unsigned short* __restrict__ ctx) {
  __shared__ __align__(16) unsigned short As[64 * 40];
  __shared__ __align__(16) unsigned short Bs[128 * 32];
  const int idx = blockIdx.x;
  const int qt = idx & 7, bh = idx >> 3;
  const int q0 = qt * 64;
  const int tid = threadIdx.x, lane = tid & 63, w = tid >> 6;
  const int lanelo = lane & 15, quad = lane >> 4;
  const int rloc4 = lane >> 2, pch4 = lane & 3;
  const int lch4 = (pch4 - rloc4) & 3;
  const int pB = (quad + lanelo) & 3;
  const f32x4 zf = {0.f, 0.f, 0.f, 0.f};
  f32x4 acc[8];
#pragma unroll
  for (int j = 0; j < 8; ++j) acc[j] = zf;

  for (int kt = 0; kt < 19; ++kt) {
    {  // stage A (64x32): 256 chunks of 8, manual (fp32 pack / abuf)
      int c = tid;
      int r = c >> 2, cc = c & 3;
      if (kt < 16) {
        const float* src = attn + ((size_t)bh * 512 + q0 + r) * 512 + kt * 32 + cc * 8;
        *(uint2*)(&As[r * 40 + cc * 8]) = pack4(*(const float4*)(src));
        *(uint2*)(&As[r * 40 + cc * 8 + 4]) = pack4(*(const float4*)(src + 4));
      } else {
        *(uint4*)(&As[r * 40 + cc * 8]) =
            *(const uint4*)(abuf + ((size_t)bh * 512 + q0 + r) * 96 + (kt - 16) * 32 + cc * 8);
      }
    }
#pragma unroll
    for (int q = 0; q < 2; ++q) {   // B: 8 segments of 16 rows; 2 per wave
      int seg = w * 2 + q;
      int grow = seg * 16 + rloc4;  // 0..127
      if (kt < 16)
        gld16(vT + ((size_t)bh * 128 + grow) * 512 + kt * 32 + lch4 * 8, &Bs[seg * 512]);
      else
        gld16(relT + grow * 96 + (kt - 16) * 32 + lch4 * 8, &Bs[seg * 512]);
    }
    __syncthreads();
    bf16x8 a = *(const bf16x8*)(&As[(w * 16 + lanelo) * 40 + quad * 8]);
#pragma unroll
    for (int j = 0; j < 8; ++j) {
      bf16x8 bb = *(const bf16x8*)(&Bs[(j * 16 + lanelo) * 32 + pB * 8]);
      acc[j] = MFMA16(a, bb, acc[j]);
    }
    __syncthreads();
  }
  const int b = bh >> 3, h = bh & 7;
#pragma unroll
  for (int j = 0; j < 8; ++j) {
    int d = j * 16 + lanelo;
#pragma unroll
    for (int i = 0; i < 4; ++i) {
      int qg = q0 + w * 16 + quad * 4 + i;
      ctx[((size_t)(b * 512 + qg)) * 1024 + h * 128 + d] = f2bf(acc[j][i]);
    }
  }
}

// ---------------------------------------------------------------------------
// K7: out = ctx @ Wo^T + bo. 128x128 tiles, DMA staging w/ rot8 swizzle.
// ---------------------------------------------------------------------------
__global__ __launch_bounds__(256) void out_proj(
    const unsigned short* __restrict__ ctx, const unsigned short* __restrict__ Wob,
    const float* __restrict__ bo, float* __restrict__ outp) {
  __shared__ __align__(16) unsigned short As[128 * 64];
  __shared__ __align__(16) unsigned short Bs[128 * 64];
  const int bm = blockIdx.x & 31, bn = blockIdx.x >> 5;
  const int tid = threadIdx.x, lane = tid & 63, w = tid >> 6;
  const int wm = (w >> 1) * 64, wn = (w & 1) * 64;
  const int lanelo = lane & 15, quad = lane >> 4;
  const int row0 = bm * 128, col0 = bn * 128;
  const int rloc = lane >> 3, pch = lane & 7;
  const int lch = (pch - rloc) & 7;
  f32x4 acc[4][4];
  const f32x4 zf = {0.f, 0.f, 0.f, 0.f};
#pragma unroll
  for (int i = 0; i < 4; ++i)
#pragma unroll
    for (int j = 0; j < 4; ++j) acc[i][j] = zf;

  for (int kt = 0; kt < 16; ++kt) {
#pragma unroll
    for (int q = 0; q < 4; ++q) {
      int seg = w * 4 + q;
      int grow = seg * 8 + rloc;
      gld16(ctx + (size_t)(row0 + grow) * 1024 + kt * 64 + lch * 8, &As[seg * 512]);
      gld16(Wob + (size_t)(col0 + grow) * 1024 + kt * 64 + lch * 8, &Bs[seg * 512]);
    }
    __syncthreads();
#pragma unroll
    for (int ks = 0; ks < 2; ++ks) {
      const int pA = (ks * 4 + quad + lanelo) & 7;
      bf16x8 a[4], bb[4];
#pragma unroll
      for (int i = 0; i < 4; ++i)
        a[i] = *(const bf16x8*)(&As[(wm + i * 16 + lanelo) * 64 + pA * 8]);
#pragma unroll
      for (int j = 0; j < 4; ++j)
        bb[j] = *(const bf16x8*)(&Bs[(wn + j * 16 + lanelo) * 64 + pA * 8]);
#pragma unroll
      for (int i = 0; i < 4; ++i)
#pragma unroll
        for (int j = 0; j < 4; ++j) acc[i][j] = MFMA16(a[i], bb[j], acc[i][j]);
    }
    __syncthreads();
  }
#pragma unroll
  for (int i = 0; i < 4; ++i) {
#pragma unroll
    for (int j = 0; j < 4; ++j) {
      int n = col0 + wn + j * 16 + lanelo;
      float bbv = bo[n];
#pragma unroll
      for (int r = 0; r < 4; ++r) {
        int m = row0 + wm + i * 16 + quad * 4 + r;
        outp[(size_t)m * 1024 + n] = acc[i][j][r] + bbv;
      }
    }
  }
}

// ---------------------------------------------------------------------------
extern "C" void kernel_launch(void* const* d_in, const int* in_sizes, int n_in,
                              void* d_out, int out_size, void* d_ws, size_t ws_size,
                              hipStream_t stream) {
  const float* x    = (const float*)d_in[0];
  const int*   mask = (const int*)d_in[1];
  const float* Wq   = (const float*)d_in[2];
  const float* bq   = (const float*)d_in[3];
  const float* Wk   = (const float*)d_in[4];
  const float* bk   = (const float*)d_in[5];
  const float* Wv   = (const float*)d_in[6];
  const float* bv   = (const float*)d_in[7];
  const float* Wo   = (const float*)d_in[8];
  const float* bo   = (const float*)d_in[9];
  const float* rel  = (const float*)d_in[10];
  const float* Wihf = (const float*)d_in[11];
  const float* Whhf = (const float*)d_in[12];
  const float* bihf = (const float*)d_in[13];
  const float* bhhf = (const float*)d_in[14];
  const float* Wihb = (const float*)d_in[15];
  const float* Whhb = (const float*)d_in[16];
  const float* bihb = (const float*)d_in[17];
  const float* bhhb = (const float*)d_in[18];

  // ws: 33,595,904 bytes used (proven-safe <= 33,702,144)
  char* ws = (char*)d_ws;
  unsigned short* qb   = (unsigned short*)(ws + 0);          // 8,388,608 B
  unsigned short* kb   = (unsigned short*)(ws + 8388608);    // 8,388,608 B
  unsigned short* vT   = (unsigned short*)(ws + 16777216);   // 8,388,608 B
  unsigned short* abuf = (unsigned short*)(ws + 25165824);   // 6,291,456 B (32768x96)
  unsigned short* relb = (unsigned short*)(ws + 31457280);   //    16,640 B
  unsigned short* relT = (unsigned short*)(ws + 31473920);   //    24,576 B
  unsigned short* Wob  = (unsigned short*)(ws + 31498496);   // 2,097,152 B
  unsigned short* ctx  = qb;   // qb dead after scores_softmax

  float* outp  = (float*)d_out;
  float* attnF = outp + 4194304;                 // (B,H,S,S) fp32 = 67.1 MB
  // bf16 scratch inside the attn region; all dead before scores_softmax
  // overwrites the whole region with fp32 attn:
  unsigned short* abase  = (unsigned short*)attnF;
  unsigned short* xb     = abase;                 // 4,194,304 elems
  unsigned short* vb     = abase + 4194304;       // 4,194,304 elems
  unsigned short* rnnout = abase + 8388608;       // 6,291,456 elems
  unsigned short* Wqkvb  = abase + 14680064;      // 3,145,728 elems
  unsigned short* Wrnnb  = abase + 17825792;      //    65,536 elems

  prep_bf16<<<dim3(8256), dim3(256), 0, stream>>>(
      x, Wq, Wk, Wv, Wo, Wihf, Whhf, Wihb, Whhb, xb, Wqkvb, Wob, Wrnnb);
  prep_rel<<<dim3(48), dim3(256), 0, stream>>>(rel, relb, relT);
  qkv_proj<<<dim3(768), dim3(256), 0, stream>>>(xb, Wqkvb, bq, bk, bv, mask,
                                                qb, kb, vb, vT);
  rnn_fused<<<dim3(768), dim3(256), 0, stream>>>(qb, kb, vb, Wrnnb,
                                                 bihf, bhhf, bihb, bhhb, rnnout);
  rnn_copyback<<<dim3(24576), dim3(256), 0, stream>>>(rnnout, qb, kb, vT);
  scores_softmax<<<dim3(512), dim3(256), 0, stream>>>(qb, kb, relb, mask, attnF, abuf);
  av_ctx<<<dim3(512), dim3(256), 0, stream>>>(attnF, abuf, vT, relT, ctx);
  out_proj<<<dim3(256), dim3(256), 0, stream>>>(ctx, Wob, bo, outp);
}